// Round 6
// baseline (2226.707 us; speedup 1.0000x reference)
//
#include <hip/hip_runtime.h>

// Problem constants
#define LL   8
#define HH   4
#define QQ   64
#define DD   512
#define NN   2048
#define DFFC 2048
#define ENTRY_CAP (1 << 17)
#define CHUNK 8
#define APPLY_BLOCKS 2048
#define LCAP 2048     // per-block LDS entry staging capacity
#define ZWORDS 149600 // rowmaxU(8192)+rowcnt(8192)+colcnt(2048)+tmaxU(131072)+tix(64)+done(32)

typedef short     bf16x8 __attribute__((ext_vector_type(8)));  // 8 bf16 = 4 VGPR
typedef float     f32x4  __attribute__((ext_vector_type(4)));  // MFMA C/D frag
typedef unsigned short u16;

// fp32 -> (hi, lo) bf16 split, RNE. x ~= hi + lo with ~16-bit mantissa coverage.
__device__ inline void splitf(float v, u16& h, u16& l)
{
    unsigned u  = __float_as_uint(v);
    unsigned uh = u + (0x7FFFu + ((u >> 16) & 1u));
    h = (u16)(uh >> 16);
    float fh = __uint_as_float(((unsigned)h) << 16);
    float r  = v - fh;
    unsigned ur = __float_as_uint(r);
    unsigned ul = ur + (0x7FFFu + ((ur >> 16) & 1u));
    l = (u16)(ul >> 16);
}

// Monotone fp32 <-> uint mapping for atomicMax on floats (no NaNs in data).
__device__ inline unsigned mapf(float f)
{
    unsigned u = __float_as_uint(f);
    return (u >> 31) ? ~u : (u | 0x80000000u);
}
__device__ inline float unmapf(unsigned u)
{
    return (u >> 31) ? __uint_as_float(u ^ 0x80000000u) : __uint_as_float(~u);
}

// ---------------------------------------------------------------------------
// 8-wave split-bf16 MFMA GEMM (NT): C[M,N] = A[M,K] @ B[N,K]^T as
// hi*hi + hi*lo + lo*hi (fp32 accumulate). 512 thr = 8 waves (4 wy x 2 wx),
// tile 128x128, BK=32, double-buffered 2x32KB LDS via global_load_lds w=16.
// XCD-aware swizzle for L2 locality. Used for FF1 only (others fused below).
// ---------------------------------------------------------------------------
template <int BIAS, int RELU, int WF32, int WSPLIT>
__global__ __launch_bounds__(512, 2) void mgemm8_k(
    const u16* __restrict__ Ahi, const u16* __restrict__ Alo,
    const u16* __restrict__ Bhi, const u16* __restrict__ Blo,
    float* __restrict__ C, u16* __restrict__ Chi, u16* __restrict__ Clo,
    const float* __restrict__ bias,
    int K, int lda, int ldb, int ldc,
    long sAoff, long sBoff, long sCoff)
{
    __shared__ __align__(16) u16 smem[2 * 2048 * 8];   // 64 KB

    const int bz = blockIdx.z;
    Ahi += bz * sAoff;  Alo += bz * sAoff;
    Bhi += bz * sBoff;  Blo += bz * sBoff;
    const long cOff = (long)bz * sCoff;

    const int gx = gridDim.x, nwg = gx * gridDim.y;
    int lin = blockIdx.y * gx + blockIdx.x;
    lin = (lin & 7) * (nwg >> 3) + (lin >> 3);
    const int bx = lin % gx, by = lin / gx;

    const int tid  = threadIdx.x;
    const int lane = tid & 63;
    const int wave = tid >> 6;
    const int quad = lane >> 4, l15 = lane & 15;
    const int wy = wave >> 1, wx = wave & 1;
    const long mTile = (long)by * 128;
    const long nTile = (long)bx * 128;

    const int fsw = (l15 & 3) ^ ((l15 >> 2) & 3);
    const int cA  = (quad ^ fsw) * 8;

    const int sr = tid >> 2;
    const int sc = (tid & 3) ^ ((sr & 3) ^ ((sr >> 2) & 3));
    const long aoff = (mTile + sr) * (long)lda + sc * 8;
    const long boff = (nTile + sr) * (long)ldb + sc * 8;

#define STAGE8(bufi, koff)                                                    \
    {                                                                         \
        u16* lb = (u16*)smem + (bufi) * (2048 * 8) + tid * 8;                 \
        __builtin_amdgcn_global_load_lds(                                     \
            (const __attribute__((address_space(1))) void*)(Ahi + aoff + (koff)), \
            (__attribute__((address_space(3))) void*)(lb), 16, 0, 0);         \
        __builtin_amdgcn_global_load_lds(                                     \
            (const __attribute__((address_space(1))) void*)(Alo + aoff + (koff)), \
            (__attribute__((address_space(3))) void*)(lb + 512 * 8), 16, 0, 0); \
        __builtin_amdgcn_global_load_lds(                                     \
            (const __attribute__((address_space(1))) void*)(Bhi + boff + (koff)), \
            (__attribute__((address_space(3))) void*)(lb + 1024 * 8), 16, 0, 0); \
        __builtin_amdgcn_global_load_lds(                                     \
            (const __attribute__((address_space(1))) void*)(Blo + boff + (koff)), \
            (__attribute__((address_space(3))) void*)(lb + 1536 * 8), 16, 0, 0); \
    }

    f32x4 acc[2][4];
#pragma unroll
    for (int i = 0; i < 2; i++)
#pragma unroll
        for (int j = 0; j < 4; j++)
            acc[i][j] = (f32x4){0.f, 0.f, 0.f, 0.f};

    STAGE8(0, 0)
    int buf = 0;
    const int NT = K >> 5;
    for (int t = 0; t < NT; t++) {
        __syncthreads();
        if (t + 1 < NT) STAGE8(buf ^ 1, (t + 1) << 5)

        const u16* Lb = (const u16*)smem + buf * (2048 * 8);
        bf16x8 ah[2], al[2], bh[4], bl[4];
#pragma unroll
        for (int i = 0; i < 2; i++) {
            const int off = (wy * 32 + i * 16 + l15) * 32 + cA;
            ah[i] = *(const bf16x8*)(Lb + off);
            al[i] = *(const bf16x8*)(Lb + 512 * 8 + off);
        }
#pragma unroll
        for (int j = 0; j < 4; j++) {
            const int off = (wx * 64 + j * 16 + l15) * 32 + cA;
            bh[j] = *(const bf16x8*)(Lb + 1024 * 8 + off);
            bl[j] = *(const bf16x8*)(Lb + 1536 * 8 + off);
        }

#pragma unroll
        for (int i = 0; i < 2; i++)
#pragma unroll
            for (int j = 0; j < 4; j++) {
                acc[i][j] = __builtin_amdgcn_mfma_f32_16x16x32_bf16(
                    ah[i], bh[j], acc[i][j], 0, 0, 0);
                acc[i][j] = __builtin_amdgcn_mfma_f32_16x16x32_bf16(
                    ah[i], bl[j], acc[i][j], 0, 0, 0);
                acc[i][j] = __builtin_amdgcn_mfma_f32_16x16x32_bf16(
                    al[i], bh[j], acc[i][j], 0, 0, 0);
            }
        buf ^= 1;
    }
#undef STAGE8

    const int mBase = (int)mTile + wy * 32;
    const int nBase = (int)nTile + wx * 64;
#pragma unroll
    for (int i = 0; i < 2; i++) {
#pragma unroll
        for (int j = 0; j < 4; j++) {
            const int n = nBase + j * 16 + l15;
            const float bv = BIAS ? bias[n] : 0.0f;
#pragma unroll
            for (int r = 0; r < 4; r++) {
                const int m = mBase + i * 16 + quad * 4 + r;
                float v = acc[i][j][r] + bv;
                if (RELU) v = fmaxf(v, 0.0f);
                const long o = cOff + (long)m * ldc + n;
                if (WF32) C[o] = v;
                if (WSPLIT) {
                    u16 h, l;
                    splitf(v, h, l);
                    Chi[o] = h;
                    Clo[o] = l;
                }
            }
        }
    }
}

// ---------------------------------------------------------------------------
// FUSED Yt + KXT kernel: grid (4, 16, 5).
//   z = 0..3 : Yt_h = XT @ V_h^T [2048,512] fp32   (XCD-swizzled tiles)
//   z = 4    : KXT  = XT @ Kw^T  [2048,256] -> hi/lo split (bx<2 active;
//              all z=4 blocks first zero-sweep the per-layer mask scratch)
// Per-element MFMA sequence (t ascending x {hh,hl,lh}) identical to prior
// rounds -> KXT bits unchanged -> mask path bit-identical.
// ---------------------------------------------------------------------------
__global__ __launch_bounds__(512, 2) void xv_k(
    const u16* __restrict__ Xhi, const u16* __restrict__ Xlo,
    const u16* __restrict__ Vhi, const u16* __restrict__ Vlo,
    const u16* __restrict__ Khi, const u16* __restrict__ Klo,
    float* __restrict__ Yt, u16* __restrict__ KXThi, u16* __restrict__ KXTlo,
    unsigned* __restrict__ zbase)
{
    __shared__ __align__(16) u16 smem[2 * 2048 * 8];   // 64 KB

    const int bz = blockIdx.z;
    const int tid = threadIdx.x;
    const bool isK = (bz == 4);

    int bx, by;
    if (!isK) {
        const int gx = 4, nwg = 64;
        int lin = blockIdx.y * gx + blockIdx.x;
        lin = (lin & 7) * (nwg >> 3) + (lin >> 3);
        bx = lin % gx;  by = lin / gx;
    } else {
        // zero-sweep of the per-layer mask scratch (all 64 z=4 blocks)
        const int gtid = (blockIdx.y * 4 + blockIdx.x) * 512 + tid;
        for (int i = gtid; i < ZWORDS; i += 64 * 512) zbase[i] = 0u;
        if (blockIdx.x >= 2) return;     // KXT has only 2 column tiles
        bx = blockIdx.x;  by = blockIdx.y;
    }

    const u16* Bh = isK ? Khi : (Vhi + (long)bz * DD * DD);
    const u16* Bl = isK ? Klo : (Vlo + (long)bz * DD * DD);
    const int ldc = isK ? (HH * QQ) : DD;
    const long cOff = isK ? 0 : (long)bz * NN * DD;

    const int lane = tid & 63;
    const int wave = tid >> 6;
    const int quad = lane >> 4, l15 = lane & 15;
    const int wy = wave >> 1, wx = wave & 1;
    const long mTile = (long)by * 128;
    const long nTile = (long)bx * 128;

    const int fsw = (l15 & 3) ^ ((l15 >> 2) & 3);
    const int cA  = (quad ^ fsw) * 8;

    const int sr = tid >> 2;
    const int sc = (tid & 3) ^ ((sr & 3) ^ ((sr >> 2) & 3));
    const long aoff = (mTile + sr) * (long)DD + sc * 8;
    const long boff = (nTile + sr) * (long)DD + sc * 8;

#define STAGEX(bufi, koff)                                                    \
    {                                                                         \
        u16* lb = (u16*)smem + (bufi) * (2048 * 8) + tid * 8;                 \
        __builtin_amdgcn_global_load_lds(                                     \
            (const __attribute__((address_space(1))) void*)(Xhi + aoff + (koff)), \
            (__attribute__((address_space(3))) void*)(lb), 16, 0, 0);         \
        __builtin_amdgcn_global_load_lds(                                     \
            (const __attribute__((address_space(1))) void*)(Xlo + aoff + (koff)), \
            (__attribute__((address_space(3))) void*)(lb + 512 * 8), 16, 0, 0); \
        __builtin_amdgcn_global_load_lds(                                     \
            (const __attribute__((address_space(1))) void*)(Bh + boff + (koff)), \
            (__attribute__((address_space(3))) void*)(lb + 1024 * 8), 16, 0, 0); \
        __builtin_amdgcn_global_load_lds(                                     \
            (const __attribute__((address_space(1))) void*)(Bl + boff + (koff)), \
            (__attribute__((address_space(3))) void*)(lb + 1536 * 8), 16, 0, 0); \
    }

    f32x4 acc[2][4];
#pragma unroll
    for (int i = 0; i < 2; i++)
#pragma unroll
        for (int j = 0; j < 4; j++)
            acc[i][j] = (f32x4){0.f, 0.f, 0.f, 0.f};

    STAGEX(0, 0)
    int buf = 0;
    for (int t = 0; t < 16; t++) {       // K = 512
        __syncthreads();
        if (t + 1 < 16) STAGEX(buf ^ 1, (t + 1) << 5)

        const u16* Lb = (const u16*)smem + buf * (2048 * 8);
        bf16x8 ah[2], al[2], bh[4], bl[4];
#pragma unroll
        for (int i = 0; i < 2; i++) {
            const int off = (wy * 32 + i * 16 + l15) * 32 + cA;
            ah[i] = *(const bf16x8*)(Lb + off);
            al[i] = *(const bf16x8*)(Lb + 512 * 8 + off);
        }
#pragma unroll
        for (int j = 0; j < 4; j++) {
            const int off = (wx * 64 + j * 16 + l15) * 32 + cA;
            bh[j] = *(const bf16x8*)(Lb + 1024 * 8 + off);
            bl[j] = *(const bf16x8*)(Lb + 1536 * 8 + off);
        }

#pragma unroll
        for (int i = 0; i < 2; i++)
#pragma unroll
            for (int j = 0; j < 4; j++) {
                acc[i][j] = __builtin_amdgcn_mfma_f32_16x16x32_bf16(
                    ah[i], bh[j], acc[i][j], 0, 0, 0);
                acc[i][j] = __builtin_amdgcn_mfma_f32_16x16x32_bf16(
                    ah[i], bl[j], acc[i][j], 0, 0, 0);
                acc[i][j] = __builtin_amdgcn_mfma_f32_16x16x32_bf16(
                    al[i], bh[j], acc[i][j], 0, 0, 0);
            }
        buf ^= 1;
    }
#undef STAGEX

    const int mBase = (int)mTile + wy * 32;
    const int nBase = (int)nTile + wx * 64;
#pragma unroll
    for (int i = 0; i < 2; i++) {
#pragma unroll
        for (int j = 0; j < 4; j++) {
            const int n = nBase + j * 16 + l15;
#pragma unroll
            for (int r = 0; r < 4; r++) {
                const int m = mBase + i * 16 + quad * 4 + r;
                const float v = acc[i][j][r];
                const long o = cOff + (long)m * ldc + n;
                if (!isK) {
                    Yt[o] = v;
                } else {
                    u16 h, l;
                    splitf(v, h, l);
                    KXThi[o] = h;
                    KXTlo[o] = l;
                }
            }
        }
    }
}

// ---------------------------------------------------------------------------
// FUSED FF2 + split-K fixup: grid (4,16,4), z = K-slice. Each block writes
// its fp32 partial into Cpart[z]; the 4th-arriving block per output tile
// (device-scope ticket in tix[]) reduces the 4 partials + b2 + attnT and
// writes Xn / attnT / Xhi / Xlo. Summation order identical to old ff2red.
// ---------------------------------------------------------------------------
__global__ __launch_bounds__(512, 2) void ff2_k(
    const u16* __restrict__ Ahi, const u16* __restrict__ Alo,
    const u16* __restrict__ Bhi, const u16* __restrict__ Blo,
    float* __restrict__ Cpart, const float* __restrict__ b2,
    float* __restrict__ attnT, float* __restrict__ Xn,
    u16* __restrict__ Xhi, u16* __restrict__ Xlo,
    int* __restrict__ tix)
{
    __shared__ __align__(16) u16 smem[2 * 2048 * 8];   // 64 KB

    const int bz = blockIdx.z;
    Ahi += bz * 512;  Alo += bz * 512;     // K-slice offset along K (u16)
    Bhi += bz * 512;  Blo += bz * 512;
    float* Cz = Cpart + (long)bz * NN * DD;

    const int gx = gridDim.x, nwg = gx * gridDim.y;
    int lin = blockIdx.y * gx + blockIdx.x;
    lin = (lin & 7) * (nwg >> 3) + (lin >> 3);
    const int bx = lin % gx, by = lin / gx;

    const int tid  = threadIdx.x;
    const int lane = tid & 63;
    const int wave = tid >> 6;
    const int quad = lane >> 4, l15 = lane & 15;
    const int wy = wave >> 1, wx = wave & 1;
    const long mTile = (long)by * 128;
    const long nTile = (long)bx * 128;

    const int fsw = (l15 & 3) ^ ((l15 >> 2) & 3);
    const int cA  = (quad ^ fsw) * 8;

    const int sr = tid >> 2;
    const int sc = (tid & 3) ^ ((sr & 3) ^ ((sr >> 2) & 3));
    const long aoff = (mTile + sr) * (long)DFFC + sc * 8;
    const long boff = (nTile + sr) * (long)DFFC + sc * 8;

#define STAGEF(bufi, koff)                                                    \
    {                                                                         \
        u16* lb = (u16*)smem + (bufi) * (2048 * 8) + tid * 8;                 \
        __builtin_amdgcn_global_load_lds(                                     \
            (const __attribute__((address_space(1))) void*)(Ahi + aoff + (koff)), \
            (__attribute__((address_space(3))) void*)(lb), 16, 0, 0);         \
        __builtin_amdgcn_global_load_lds(                                     \
            (const __attribute__((address_space(1))) void*)(Alo + aoff + (koff)), \
            (__attribute__((address_space(3))) void*)(lb + 512 * 8), 16, 0, 0); \
        __builtin_amdgcn_global_load_lds(                                     \
            (const __attribute__((address_space(1))) void*)(Bhi + boff + (koff)), \
            (__attribute__((address_space(3))) void*)(lb + 1024 * 8), 16, 0, 0); \
        __builtin_amdgcn_global_load_lds(                                     \
            (const __attribute__((address_space(1))) void*)(Blo + boff + (koff)), \
            (__attribute__((address_space(3))) void*)(lb + 1536 * 8), 16, 0, 0); \
    }

    f32x4 acc[2][4];
#pragma unroll
    for (int i = 0; i < 2; i++)
#pragma unroll
        for (int j = 0; j < 4; j++)
            acc[i][j] = (f32x4){0.f, 0.f, 0.f, 0.f};

    STAGEF(0, 0)
    int buf = 0;
    for (int t = 0; t < 16; t++) {       // per-slice K = 512
        __syncthreads();
        if (t + 1 < 16) STAGEF(buf ^ 1, (t + 1) << 5)

        const u16* Lb = (const u16*)smem + buf * (2048 * 8);
        bf16x8 ah[2], al[2], bh[4], bl[4];
#pragma unroll
        for (int i = 0; i < 2; i++) {
            const int off = (wy * 32 + i * 16 + l15) * 32 + cA;
            ah[i] = *(const bf16x8*)(Lb + off);
            al[i] = *(const bf16x8*)(Lb + 512 * 8 + off);
        }
#pragma unroll
        for (int j = 0; j < 4; j++) {
            const int off = (wx * 64 + j * 16 + l15) * 32 + cA;
            bh[j] = *(const bf16x8*)(Lb + 1024 * 8 + off);
            bl[j] = *(const bf16x8*)(Lb + 1536 * 8 + off);
        }

#pragma unroll
        for (int i = 0; i < 2; i++)
#pragma unroll
            for (int j = 0; j < 4; j++) {
                acc[i][j] = __builtin_amdgcn_mfma_f32_16x16x32_bf16(
                    ah[i], bh[j], acc[i][j], 0, 0, 0);
                acc[i][j] = __builtin_amdgcn_mfma_f32_16x16x32_bf16(
                    ah[i], bl[j], acc[i][j], 0, 0, 0);
                acc[i][j] = __builtin_amdgcn_mfma_f32_16x16x32_bf16(
                    al[i], bh[j], acc[i][j], 0, 0, 0);
            }
        buf ^= 1;
    }
#undef STAGEF

    const int mBase = (int)mTile + wy * 32;
    const int nBase = (int)nTile + wx * 64;
#pragma unroll
    for (int i = 0; i < 2; i++)
#pragma unroll
        for (int j = 0; j < 4; j++) {
            const int n = nBase + j * 16 + l15;
#pragma unroll
            for (int r = 0; r < 4; r++) {
                const int m = mBase + i * 16 + quad * 4 + r;
                Cz[(long)m * DD + n] = acc[i][j][r];
            }
        }

    // split-K fixup: 4th-arriving block per tile reduces and finalizes.
    __threadfence();
    __shared__ int lastZ;
    const int tileId = by * 4 + bx;
    if (tid == 0) lastZ = (atomicAdd(&tix[tileId], 1) == 3);
    __syncthreads();
    if (!lastZ) return;
    __threadfence();

    const float4* C0 = (const float4*)Cpart;
    const float4* C1 = (const float4*)(Cpart + (long)NN * DD);
    const float4* C2 = (const float4*)(Cpart + 2L * NN * DD);
    const float4* C3 = (const float4*)(Cpart + 3L * NN * DD);
    const float4* b2f = (const float4*)b2;
    const int ncol4 = (int)(nTile >> 2);
#pragma unroll
    for (int it = 0; it < 8; it++) {
        const int e  = it * 512 + tid;       // 4096 float4 per 128x128 tile
        const int r  = e >> 5;
        const int c4 = e & 31;
        const long o4 = (mTile + r) * 128 + ncol4 + c4;
        float4 v0 = C0[o4], v1 = C1[o4], v2 = C2[o4], v3 = C3[o4];
        float4 bv = b2f[ncol4 + c4];
        float4 rv = ((const float4*)attnT)[o4];
        float4 o;
        o.x = v0.x + v1.x + v2.x + v3.x + bv.x + rv.x;
        o.y = v0.y + v1.y + v2.y + v3.y + bv.y + rv.y;
        o.z = v0.z + v1.z + v2.z + v3.z + bv.z + rv.z;
        o.w = v0.w + v1.w + v2.w + v3.w + bv.w + rv.w;
        ((float4*)Xn)[o4] = o;
        ((float4*)attnT)[o4] = o;       // seed next layer's residual base
        ushort4 hv, lv;
        splitf(o.x, hv.x, lv.x);
        splitf(o.y, hv.y, lv.y);
        splitf(o.z, hv.z, lv.z);
        splitf(o.w, hv.w, lv.w);
        ((ushort4*)Xhi)[o4] = hv;
        ((ushort4*)Xlo)[o4] = lv;
    }
}

// ---------------------------------------------------------------------------
// Fused mask path, pass A: per-head Gram tile S = G G^T via one-shot LDS
// staging. MFMA order (s{i{j{hh,hl,lh}}}) IDENTICAL to sextract_k -> same
// bits. Publishes per-tile per-row maxima (tmaxU) for pass-B early exit.
// ---------------------------------------------------------------------------
__global__ __launch_bounds__(256, 2) void smax_k(
    const u16* __restrict__ Ghi, const u16* __restrict__ Glo,
    unsigned* __restrict__ rowmaxU, unsigned* __restrict__ tmaxU)
{
    __shared__ __align__(16) u16 gs[4096 * 8];   // 64 KB: Ahi|Alo|Bhi|Blo
    const int h = blockIdx.z;
    const int lda = HH * QQ;
    const u16* Gh = Ghi + h * QQ;
    const u16* Gl = Glo + h * QQ;

    const int gx = gridDim.x, nwg = gx * gridDim.y;   // 16, 256
    int lin = blockIdx.y * gx + blockIdx.x;
    lin = (lin & 7) * (nwg >> 3) + (lin >> 3);
    const int bxs = lin % gx, bys = lin / gx;

    const int tid  = threadIdx.x;
    const int wave = tid >> 6, lane = tid & 63;
    const int quad = lane >> 4, l15 = lane & 15;
    const int wy = wave >> 1, wx = wave & 1;
    const int rT = bys * 128, cT = bxs * 128;
    const int rB = rT + wy * 64;

#define SSTG(src, rowbase, dstbase)                                           \
    _Pragma("unroll")                                                         \
    for (int it = 0; it < 4; it++) {                                          \
        const int idx = it * 256 + tid;                                       \
        const int r = idx >> 3;                                               \
        const int c = (idx & 7) ^ (r & 7);                                    \
        __builtin_amdgcn_global_load_lds(                                     \
            (const __attribute__((address_space(1))) void*)(src + (long)((rowbase) + r) * lda + c * 8), \
            (__attribute__((address_space(3))) void*)((u16*)gs + (dstbase) + idx * 8), 16, 0, 0); \
    }
    SSTG(Gh, rT, 0)
    SSTG(Gl, rT, 8192)
    SSTG(Gh, cT, 16384)
    SSTG(Gl, cT, 24576)
#undef SSTG
    __syncthreads();

    bf16x8 ah[2][4], al[2][4], bh[2][4], bl[2][4];
#pragma unroll
    for (int s = 0; s < 2; s++) {
#pragma unroll
        for (int i = 0; i < 4; i++) {
            const int ra = wy * 64 + i * 16 + l15;
            const int ca = ((s * 4 + quad) ^ (ra & 7)) * 8;
            ah[s][i] = *(const bf16x8*)(gs + ra * 64 + ca);
            al[s][i] = *(const bf16x8*)(gs + 8192 + ra * 64 + ca);
            const int rb = wx * 64 + i * 16 + l15;
            const int cb = ((s * 4 + quad) ^ (rb & 7)) * 8;
            bh[s][i] = *(const bf16x8*)(gs + 16384 + rb * 64 + cb);
            bl[s][i] = *(const bf16x8*)(gs + 24576 + rb * 64 + cb);
        }
    }

    f32x4 acc[4][4];
#pragma unroll
    for (int i = 0; i < 4; i++)
#pragma unroll
        for (int j = 0; j < 4; j++)
            acc[i][j] = (f32x4){0.f, 0.f, 0.f, 0.f};

#pragma unroll
    for (int s = 0; s < 2; s++)
#pragma unroll
        for (int i = 0; i < 4; i++)
#pragma unroll
            for (int j = 0; j < 4; j++) {
                acc[i][j] = __builtin_amdgcn_mfma_f32_16x16x32_bf16(ah[s][i], bh[s][j], acc[i][j], 0, 0, 0);
                acc[i][j] = __builtin_amdgcn_mfma_f32_16x16x32_bf16(ah[s][i], bl[s][j], acc[i][j], 0, 0, 0);
                acc[i][j] = __builtin_amdgcn_mfma_f32_16x16x32_bf16(al[s][i], bh[s][j], acc[i][j], 0, 0, 0);
            }

    const unsigned tBase = (unsigned)((((h << 4) + bys) << 4) + bxs) * 128u;
#pragma unroll
    for (int i = 0; i < 4; i++)
#pragma unroll
        for (int r = 0; r < 4; r++) {
            float mx = acc[i][0][r];
#pragma unroll
            for (int j = 1; j < 4; j++) mx = fmaxf(mx, acc[i][j][r]);
#pragma unroll
            for (int off = 1; off < 16; off <<= 1)
                mx = fmaxf(mx, __shfl_xor(mx, off, 64));
            if (l15 == 0) {
                const int lr = wy * 64 + i * 16 + quad * 4 + r;
                const unsigned mv = mapf(mx);
                atomicMax(&rowmaxU[h * NN + rT + lr], mv);
                atomicMax(&tmaxU[tBase + lr], mv);
            }
        }
}

// ---------------------------------------------------------------------------
// Fused mask path, pass B: EARLY-EXIT via tmaxU (exact bit-level test), else
// recompute IDENTICAL S tile, threshold, count, emit (LDS-aggregated colcnt).
// NEW: the LAST block (device-scope done-ticket) inlines the 2048-wide
// exclusive scan of colcnt -> colOff/colCur (removes the scan_k launch).
// ---------------------------------------------------------------------------
__global__ __launch_bounds__(256) void sextract_k(
    const u16* __restrict__ Ghi, const u16* __restrict__ Glo,
    const unsigned* __restrict__ rowmaxU, const unsigned* __restrict__ tmaxU,
    int* __restrict__ rowcnt, unsigned* __restrict__ colcnt,
    unsigned int* __restrict__ entries, int* __restrict__ counter,
    int* __restrict__ colOff, int* __restrict__ colCur,
    int* __restrict__ doneCnt)
{
    const int h = blockIdx.z;
    const u16* Ah = Ghi + h * QQ;
    const u16* Al = Glo + h * QQ;
    const int lda = HH * QQ;

    const int gx = gridDim.x, nwg = gx * gridDim.y;
    int lin = blockIdx.y * gx + blockIdx.x;
    lin = (lin & 7) * (nwg >> 3) + (lin >> 3);
    const int bxs = lin % gx, bys = lin / gx;

    const int tid  = threadIdx.x;
    const int wave = tid >> 6, lane = tid & 63;
    const int quad = lane >> 4, l15 = lane & 15;
    const int wy = wave >> 1, wx = wave & 1;
    const int rB = bys * 128 + wy * 64;
    const int cT = bxs * 128;
    const int cB = cT + wx * 64;

    __shared__ float thrS[128];
    __shared__ int chist[128];
    __shared__ unsigned lbuf[LCAP];
    __shared__ int lcnt, gbase, anyf, lastS;
    if (tid == 0) { lcnt = 0; anyf = 0; }
    if (tid < 128) {
        chist[tid] = 0;
        float mx = unmapf(rowmaxU[h * NN + bys * 128 + tid]);
        float thr = (fabsf(mx) > 0.5f) ? mx - 0.5f : 3.402823466e38f;
        thrS[tid] = thr;
        float tm = unmapf(tmaxU[(unsigned)((((h << 4) + bys) << 4) + bxs) * 128u + tid]);
        if (tm >= thr) atomicAdd(&anyf, 1);
    }
    __syncthreads();

    if (anyf != 0) {   // tile may contain entries (exact bit-level test)
        bf16x8 ah[2][4], al[2][4], bh[2][4], bl[2][4];
#pragma unroll
        for (int s = 0; s < 2; s++) {
            const int kk = s * 32 + quad * 8;
#pragma unroll
            for (int i = 0; i < 4; i++) {
                long ar = (long)(rB + i * 16 + l15) * lda + kk;
                ah[s][i] = *(const bf16x8*)(Ah + ar);
                al[s][i] = *(const bf16x8*)(Al + ar);
                long br = (long)(cB + i * 16 + l15) * lda + kk;
                bh[s][i] = *(const bf16x8*)(Ah + br);
                bl[s][i] = *(const bf16x8*)(Al + br);
            }
        }

        f32x4 acc[4][4];
#pragma unroll
        for (int i = 0; i < 4; i++)
#pragma unroll
            for (int j = 0; j < 4; j++)
                acc[i][j] = (f32x4){0.f, 0.f, 0.f, 0.f};

#pragma unroll
        for (int s = 0; s < 2; s++)
#pragma unroll
            for (int i = 0; i < 4; i++)
#pragma unroll
                for (int j = 0; j < 4; j++) {
                    acc[i][j] = __builtin_amdgcn_mfma_f32_16x16x32_bf16(ah[s][i], bh[s][j], acc[i][j], 0, 0, 0);
                    acc[i][j] = __builtin_amdgcn_mfma_f32_16x16x32_bf16(ah[s][i], bl[s][j], acc[i][j], 0, 0, 0);
                    acc[i][j] = __builtin_amdgcn_mfma_f32_16x16x32_bf16(al[s][i], bh[s][j], acc[i][j], 0, 0, 0);
                }

#pragma unroll
        for (int i = 0; i < 4; i++) {
#pragma unroll
            for (int r = 0; r < 4; r++) {
                const int lr  = wy * 64 + i * 16 + quad * 4 + r;
                const int row = h * NN + rB + i * 16 + quad * 4 + r;
                const float thr = thrS[lr];

                int c = 0;
#pragma unroll
                for (int j = 0; j < 4; j++) c += (acc[i][j][r] >= thr) ? 1 : 0;
                int cs = c;
#pragma unroll
                for (int off = 1; off < 16; off <<= 1) cs += __shfl_xor(cs, off, 64);
                if (l15 == 0 && cs > 0) atomicAdd(&rowcnt[row], cs);

#pragma unroll
                for (int j = 0; j < 4; j++) {
                    if (acc[i][j][r] >= thr) {
                        const unsigned m = (unsigned)(cB + j * 16 + l15);
                        unsigned ent = ((unsigned)row << 11) | m;
                        atomicAdd(&chist[m & 127], 1);
                        int s2 = atomicAdd(&lcnt, 1);
                        if (s2 < LCAP) {
                            lbuf[s2] = ent;
                        } else {
                            unsigned p = (unsigned)atomicAdd(counter, 1);
                            if (p < ENTRY_CAP) entries[p] = ent;
                        }
                    }
                }
            }
        }

        __syncthreads();
        if (tid < 128) {
            int hc = chist[tid];
            if (hc > 0) atomicAdd(&colcnt[cT + tid], (unsigned)hc);
        }
        int n = lcnt;
        if (n > LCAP) n = LCAP;
        if (n > 0) {
            if (tid == 0) gbase = atomicAdd(counter, n);
            __syncthreads();
            for (int i2 = tid; i2 < n; i2 += 256) {
                unsigned p = (unsigned)(gbase + i2);
                if (p < ENTRY_CAP) entries[p] = lbuf[i2];
            }
        }
    }

    // done-ticket: last of the 1024 blocks performs the colOff scan inline.
    __threadfence();
    if (tid == 0) lastS = (atomicAdd(doneCnt, 1) == (16 * 16 * HH - 1));
    __syncthreads();
    if (!lastS) return;
    __threadfence();
    {
        __shared__ int part[256];
        int e[8];
        int s = 0;
#pragma unroll
        for (int i = 0; i < 8; i++) { e[i] = s; s += (int)colcnt[tid * 8 + i]; }
        part[tid] = s;
        __syncthreads();
        for (int off = 1; off < 256; off <<= 1) {
            int x = (tid >= off) ? part[tid - off] : 0;
            __syncthreads();
            part[tid] += x;
            __syncthreads();
        }
        int base = (tid > 0) ? part[tid - 1] : 0;
#pragma unroll
        for (int i = 0; i < 8; i++) {
            colOff[tid * 8 + i] = base + e[i];
            colCur[tid * 8 + i] = base + e[i];
        }
        if (tid == 255) colOff[NN] = part[255];
    }
}

// ---------------------------------------------------------------------------
// Two-level scatter: per-block LDS histogram -> one colCur reservation atomic
// per distinct column per block -> LDS-cursor placement.
// ---------------------------------------------------------------------------
__global__ __launch_bounds__(256) void scatter_k(
    const unsigned int* __restrict__ entries, const int* __restrict__ counter,
    unsigned int* __restrict__ csr, int* __restrict__ colCur)
{
    __shared__ int hist[NN];   // 8 KB: per-chunk histogram, then local cursor
    __shared__ int base[NN];   // 8 KB: reserved global base per column
    int cnt = *counter;
    if (cnt > ENTRY_CAP) cnt = ENTRY_CAP;
    const int nb = gridDim.x;
    const int chunk = (cnt + nb - 1) / nb;
    const int s0 = blockIdx.x * chunk;
    int s1 = s0 + chunk;
    if (s1 > cnt) s1 = cnt;
    if (s0 >= s1) return;

    for (int i = threadIdx.x; i < NN; i += 256) hist[i] = 0;
    __syncthreads();
    for (int i = s0 + threadIdx.x; i < s1; i += 256)
        atomicAdd(&hist[entries[i] & 2047], 1);
    __syncthreads();
    for (int i = threadIdx.x; i < NN; i += 256) {
        int hcount = hist[i];
        base[i] = (hcount > 0) ? atomicAdd(&colCur[i], hcount) : 0;
        hist[i] = 0;   // reuse as local cursor
    }
    __syncthreads();
    for (int i = s0 + threadIdx.x; i < s1; i += 256) {
        unsigned v = entries[i];
        int m = v & 2047;
        int off = atomicAdd(&hist[m], 1);
        csr[base[m] + off] = v;
    }
}

// ---------------------------------------------------------------------------
// split / splitall (x2 work/thread, + counters zero) / splitc / apply /
// transpose
// ---------------------------------------------------------------------------
__global__ __launch_bounds__(256) void split_k(
    const float* __restrict__ src, u16* __restrict__ hi, u16* __restrict__ lo)
{
    int i = blockIdx.x * 256 + threadIdx.x;
    float4 v = ((const float4*)src)[i];
    ushort4 hv, lv;
    splitf(v.x, hv.x, lv.x);
    splitf(v.y, hv.y, lv.y);
    splitf(v.z, hv.z, lv.z);
    splitf(v.w, hv.w, lv.w);
    ((ushort4*)hi)[i] = hv;
    ((ushort4*)lo)[i] = lv;
}

// initial split that also seeds attnT = X^T
__global__ __launch_bounds__(256) void splitc_k(
    const float* __restrict__ src, u16* __restrict__ hi, u16* __restrict__ lo,
    float* __restrict__ cpy)
{
    int i = blockIdx.x * 256 + threadIdx.x;
    float4 v = ((const float4*)src)[i];
    ((float4*)cpy)[i] = v;
    ushort4 hv, lv;
    splitf(v.x, hv.x, lv.x);
    splitf(v.y, hv.y, lv.y);
    splitf(v.z, hv.z, lv.z);
    splitf(v.w, hv.w, lv.w);
    ((ushort4*)hi)[i] = hv;
    ((ushort4*)lo)[i] = lv;
}

// one-shot split of ALL layers' weights; 2 coalesced sweeps per thread
// (region boundaries are multiples of 256 float4) + counters zero.
__global__ __launch_bounds__(256) void splitall_k(
    const float* __restrict__ K_, const float* __restrict__ V_,
    const float* __restrict__ W1_, const float* __restrict__ W2_,
    u16* __restrict__ KhiA, u16* __restrict__ KloA,
    u16* __restrict__ VhiA, u16* __restrict__ VloA,
    u16* __restrict__ W1hiA, u16* __restrict__ W1loA,
    u16* __restrict__ W2hiA, u16* __restrict__ W2loA,
    int* __restrict__ counters)
{
    if (blockIdx.x == 0 && threadIdx.x < LL) counters[threadIdx.x] = 0;
    const int li  = blockIdx.x / 1600;
    const int sub = blockIdx.x % 1600;
#pragma unroll
    for (int jj = 0; jj < 2; jj++) {
        int i = sub * 512 + jj * 256 + threadIdx.x;  // float4 idx in layer
        const float* s;
        u16 *h, *l;
        int off;
        if (i < 32768) {
            s = K_ + (long)li * 131072;
            h = KhiA + (long)li * 131072;  l = KloA + (long)li * 131072;
            off = i;
        } else if (i < 294912) {
            s = V_ + (long)li * 1048576;
            h = VhiA + (long)li * 1048576; l = VloA + (long)li * 1048576;
            off = i - 32768;
        } else if (i < 557056) {
            s = W1_ + (long)li * 1048576;
            h = W1hiA + (long)li * 1048576; l = W1loA + (long)li * 1048576;
            off = i - 294912;
        } else {
            s = W2_ + (long)li * 1048576;
            h = W2hiA + (long)li * 1048576; l = W2loA + (long)li * 1048576;
            off = i - 557056;
        }
        float4 v = ((const float4*)s)[off];
        ushort4 hv, lv;
        splitf(v.x, hv.x, lv.x);
        splitf(v.y, hv.y, lv.y);
        splitf(v.z, hv.z, lv.z);
        splitf(v.w, hv.w, lv.w);
        ((ushort4*)h)[off] = hv;
        ((ushort4*)l)[off] = lv;
    }
}

__global__ __launch_bounds__(256) void apply_k(
    const unsigned int* __restrict__ csr, const int* __restrict__ colOff,
    const unsigned* __restrict__ rowmaxU, const int* __restrict__ rowcnt,
    const float* __restrict__ Yt, float* __restrict__ attnT)
{
    const int total = colOff[NN];
    const int tid = threadIdx.x;

    for (int base = blockIdx.x * CHUNK; base < total;
         base += gridDim.x * CHUNK) {
        int end = base + CHUNK;
        if (end > total) end = total;

        float a0 = 0.0f, a1 = 0.0f;
        int curM = -1;
        for (int e = base; e < end; e++) {
            unsigned v = csr[e];
            int m = v & 2047;
            int row = (int)(v >> 11);
            if (m != curM) {
                if (curM >= 0) {
                    atomicAdd(&attnT[(long)curM * DD + tid], a0);
                    atomicAdd(&attnT[(long)curM * DD + tid + 256], a1);
                }
                curM = m;
                a0 = a1 = 0.0f;
            }
            float mx = unmapf(rowmaxU[row]);
            float w = (fabsf(mx) > 0.5f)
                          ? 1.0f / fmaxf((float)rowcnt[row], 1.0f) : 0.0f;
            const float* y = Yt + (long)row * DD;
            a0 += w * y[tid];
            a1 += w * y[tid + 256];
        }
        if (curM >= 0) {
            atomicAdd(&attnT[(long)curM * DD + tid], a0);
            atomicAdd(&attnT[(long)curM * DD + tid + 256], a1);
        }
    }
}

__global__ __launch_bounds__(256) void transpose_k(
    const float* __restrict__ src, float* __restrict__ dst, int R, int C)
{
    __shared__ float t[32][33];
    int tx = threadIdx.x & 31, ty = threadIdx.x >> 5;
    int c0 = blockIdx.x * 32, r0 = blockIdx.y * 32;
#pragma unroll
    for (int k = 0; k < 4; k++)
        t[ty + 8 * k][tx] = src[(long)(r0 + ty + 8 * k) * C + c0 + tx];
    __syncthreads();
#pragma unroll
    for (int k = 0; k < 4; k++)
        dst[(long)(c0 + ty + 8 * k) * R + r0 + tx] = t[tx][ty + 8 * k];
}

// ---------------------------------------------------------------------------
// Workspace layout (~193 MB < 256 MiB workspace).
// ---------------------------------------------------------------------------
extern "C" void kernel_launch(void* const* d_in, const int* in_sizes, int n_in,
                              void* d_out, int out_size, void* d_ws, size_t ws_size,
                              hipStream_t stream)
{
    const float* X0 = (const float*)d_in[0];
    const float* Kw = (const float*)d_in[1];
    const float* Vw = (const float*)d_in[2];
    const float* W1 = (const float*)d_in[3];
    const float* b1 = (const float*)d_in[4];
    const float* W2 = (const float*)d_in[5];
    const float* b2 = (const float*)d_in[6];
    float* out = (float*)d_out;

    float* R0    = (float*)d_ws;
    float* Yt    = R0;                       // 4,194,304  [H,NN,DD] fp32
    u16*   ff1hi = (u16*)(R0 + 4194304);
    u16*   ff1lo = (u16*)(R0 + 6291456);
    float* Cpart = R0 + 8388608;             // 4,194,304
    float* attnT = R0 + 12582912;            // 1,048,576

    float* ext = R0 + 13631488;
    u16* KXThi = (u16*)ext;                  // 262,144 words
    u16* KXTlo = (u16*)(ext + 262144);
    float* XbufA = ext + 524288;             // 1,048,576
    float* XbufB = ext + 1572864;            // 1,048,576
    u16* Xhi  = (u16*)(ext + 2621440);       // 524,288 words
    u16* Xlo  = (u16*)(ext + 3145728);
    u16* athi = (u16*)(ext + 3670016);
    u16* atlo = (u16*)(ext + 4194304);       // (ext+4718592 .. ext+8003583 free)
    unsigned int* entries = (unsigned int*)(ext + 8003584);  // 131,072
    unsigned int* csr     = (unsigned int*)(ext + 8134656);  // 131,072
    int* colOff   = (int*)(ext + 8265728);   // 2,112
    int* counters = (int*)(ext + 8267840);   // 64
    // contiguous zero region (ZWORDS = 149,600 u32):
    unsigned* zb      = (unsigned*)(ext + 8267904);
    unsigned* rowmaxU = zb;                          // 8,192
    int*      rowcnt  = (int*)(zb + 8192);           // 8,192
    unsigned* colcnt  = zb + 16384;                  // 2,048
    unsigned* tmaxU   = zb + 18432;                  // 131,072
    int*      tix     = (int*)(zb + 149504);         // 64
    int*      done    = (int*)(zb + 149568);         // 32
    int* colCur = (int*)(ext + 8417536);             // 2,048
    // all-layer weight splits (u16), 104.9 MB:
    u16* wbase = (u16*)(ext + 8419584);
    u16* KhiA  = wbase;                         // 8 x 131,072
    u16* KloA  = wbase + 1048576;
    u16* VhiA  = wbase + 2097152;               // 8 x 1,048,576
    u16* VloA  = wbase + 10485760;
    u16* W1hiA = wbase + 18874368;
    u16* W1loA = wbase + 27262976;
    u16* W2hiA = wbase + 35651584;
    u16* W2loA = wbase + 44040192;              // ends at 52,428,800 u16

    // all-layer weight split (hoisted) + counters zero
    splitall_k<<<dim3(LL * 1600), 256, 0, stream>>>(
        Kw, Vw, W1, W2, KhiA, KloA, VhiA, VloA, W1hiA, W1loA, W2hiA, W2loA,
        counters);

    // XT0 = X0^T [N, D]; split to bf16 hi/lo and seed attnT = XT0
    transpose_k<<<dim3(NN / 32, DD / 32), 256, 0, stream>>>(X0, XbufA, DD, NN);
    splitc_k<<<dim3(1024), 256, 0, stream>>>(XbufA, Xhi, Xlo, attnT);

    float* Xc = XbufA;
    for (int li = 0; li < LL; li++) {
        float* Xn = (li & 1) ? XbufA : XbufB;
        u16* Khi = KhiA + (long)li * 131072;
        u16* Klo = KloA + (long)li * 131072;
        u16* Vhi = VhiA + (long)li * 1048576;
        u16* Vlo = VloA + (long)li * 1048576;
        u16* W1hi = W1hiA + (long)li * 1048576;
        u16* W1lo = W1loA + (long)li * 1048576;
        u16* W2hi = W2hiA + (long)li * 1048576;
        u16* W2lo = W2loA + (long)li * 1048576;

        // 1) FUSED: Yt (z=0..3) + KXT (z=4, incl. mask-scratch zero-sweep)
        xv_k<<<dim3(4, 16, 5), 512, 0, stream>>>(
            Xhi, Xlo, Vhi, Vlo, Khi, Klo, Yt, KXThi, KXTlo, zb);

        // 2) fused mask path (sextract's last block inlines the scan)
        smax_k<<<dim3(16, 16, HH), 256, 0, stream>>>(KXThi, KXTlo, rowmaxU, tmaxU);
        sextract_k<<<dim3(16, 16, HH), 256, 0, stream>>>(
            KXThi, KXTlo, rowmaxU, tmaxU, rowcnt, colcnt, entries,
            counters + li, colOff, colCur, done);
        scatter_k<<<dim3(64), 256, 0, stream>>>(entries, counters + li, csr, colCur);

        // 3) attnT (= XT residual) += sparse combine; split for FF1 input
        apply_k<<<dim3(APPLY_BLOCKS), 256, 0, stream>>>(
            csr, colOff, rowmaxU, rowcnt, Yt, attnT);
        split_k<<<dim3(1024), 256, 0, stream>>>(attnT, athi, atlo);

        // 4) ff1 = relu(attnT @ W1^T + b1) -> hi/lo. 256 blocks.
        mgemm8_k<1, 1, 0, 1><<<dim3(16, 16, 1), 512, 0, stream>>>(
            athi, atlo, W1hi, W1lo, nullptr, ff1hi, ff1lo,
            b1 + (long)li * DFFC,
            DD, DD, DD, DFFC, 0, 0, 0);

        // 5) FUSED FF2 split-K=4 + fixup (bias + residual + split + writeback)
        ff2_k<<<dim3(4, 16, 4), 512, 0, stream>>>(
            ff1hi, ff1lo, W2hi, W2lo, Cpart, b2 + (long)li * DD,
            attnT, Xn, Xhi, Xlo, tix);

        Xc = Xn;
    }

    // out = XT_final^T  [D, N]
    transpose_k<<<dim3(DD / 32, NN / 32), 256, 0, stream>>>(Xc, out, NN, DD);
}

// Round 7
// 1226.642 us; speedup vs baseline: 1.8153x; 1.8153x over previous
//
#include <hip/hip_runtime.h>

// Problem constants
#define LL   8
#define HH   4
#define QQ   64
#define DD   512
#define NN   2048
#define DFFC 2048
#define ENTRY_CAP (1 << 17)
#define CHUNK 8
#define APPLY_BLOCKS 2048
#define LCAP 2048   // per-block LDS entry staging capacity
#define ZWORDS 149504  // rowmaxU(8192)+rowcnt(8192)+colcnt(2048)+tmaxU(131072)

typedef short     bf16x8 __attribute__((ext_vector_type(8)));  // 8 bf16 = 4 VGPR
typedef float     f32x4  __attribute__((ext_vector_type(4)));  // MFMA C/D frag
typedef unsigned short u16;

// fp32 -> (hi, lo) bf16 split, RNE. x ~= hi + lo with ~16-bit mantissa coverage.
__device__ inline void splitf(float v, u16& h, u16& l)
{
    unsigned u  = __float_as_uint(v);
    unsigned uh = u + (0x7FFFu + ((u >> 16) & 1u));
    h = (u16)(uh >> 16);
    float fh = __uint_as_float(((unsigned)h) << 16);
    float r  = v - fh;
    unsigned ur = __float_as_uint(r);
    unsigned ul = ur + (0x7FFFu + ((ur >> 16) & 1u));
    l = (u16)(ul >> 16);
}

// Monotone fp32 <-> uint mapping for atomicMax on floats (no NaNs in data).
__device__ inline unsigned mapf(float f)
{
    unsigned u = __float_as_uint(f);
    return (u >> 31) ? ~u : (u | 0x80000000u);
}
__device__ inline float unmapf(unsigned u)
{
    return (u >> 31) ? __uint_as_float(u ^ 0x80000000u) : __uint_as_float(~u);
}

// ---------------------------------------------------------------------------
// 8-wave split-bf16 MFMA GEMM (NT): C[M,N] = A[M,K] @ B[N,K]^T as
// hi*hi + hi*lo + lo*hi (fp32 accumulate). 512 thr = 8 waves (4 wy x 2 wx),
// tile 128x128, BK=32, double-buffered 2x32KB LDS via global_load_lds w=16.
// XCD-aware swizzle for L2 locality. K mult of 32; M,N mult of 128.
// NOTE (round-6 post-mortem): do NOT fuse epilogues across kernels with
// device-scope tickets — the required __threadfence() (L2 wb/inv on
// non-coherent per-XCD L2s) + low-occupancy fixup tail cost far more than
// the ~4us launch gap they save (ff2_k was 110us vs ~40us for FF2+ff2red).
// ---------------------------------------------------------------------------
template <int BIAS, int RELU, int WF32, int WSPLIT>
__global__ __launch_bounds__(512, 2) void mgemm8_k(
    const u16* __restrict__ Ahi, const u16* __restrict__ Alo,
    const u16* __restrict__ Bhi, const u16* __restrict__ Blo,
    float* __restrict__ C, u16* __restrict__ Chi, u16* __restrict__ Clo,
    const float* __restrict__ bias,
    int K, int lda, int ldb, int ldc,
    long sAoff, long sBoff, long sCoff)
{
    __shared__ __align__(16) u16 smem[2 * 2048 * 8];   // 64 KB

    const int bz = blockIdx.z;
    Ahi += bz * sAoff;  Alo += bz * sAoff;
    Bhi += bz * sBoff;  Blo += bz * sBoff;
    const long cOff = (long)bz * sCoff;

    // XCD swizzle of the per-z 2D grid (nwg % 8 == 0 at every call site)
    const int gx = gridDim.x, nwg = gx * gridDim.y;
    int lin = blockIdx.y * gx + blockIdx.x;
    lin = (lin & 7) * (nwg >> 3) + (lin >> 3);
    const int bx = lin % gx, by = lin / gx;

    const int tid  = threadIdx.x;
    const int lane = tid & 63;
    const int wave = tid >> 6;
    const int quad = lane >> 4, l15 = lane & 15;
    const int wy = wave >> 1, wx = wave & 1;
    const long mTile = (long)by * 128;
    const long nTile = (long)bx * 128;

    // fragment-read chunk swizzle (row bits 0..3 == l15 for all frag rows)
    const int fsw = (l15 & 3) ^ ((l15 >> 2) & 3);
    const int cA  = (quad ^ fsw) * 8;              // u16 offset of 16B chunk

    // staging: 512 thr cover one 512-chunk stream per instruction.
    // LDS dest linear (wave-uniform base + lane*16B); global source carries
    // the inverse swizzle (chunk c holds global chunk c ^ f(row)).
    const int sr = tid >> 2;                                   // row 0..127
    const int sc = (tid & 3) ^ ((sr & 3) ^ ((sr >> 2) & 3));   // src chunk
    const long aoff = (mTile + sr) * (long)lda + sc * 8;
    const long boff = (nTile + sr) * (long)ldb + sc * 8;

#define STAGE8(bufi, koff)                                                    \
    {                                                                         \
        u16* lb = (u16*)smem + (bufi) * (2048 * 8) + tid * 8;                 \
        __builtin_amdgcn_global_load_lds(                                     \
            (const __attribute__((address_space(1))) void*)(Ahi + aoff + (koff)), \
            (__attribute__((address_space(3))) void*)(lb), 16, 0, 0);         \
        __builtin_amdgcn_global_load_lds(                                     \
            (const __attribute__((address_space(1))) void*)(Alo + aoff + (koff)), \
            (__attribute__((address_space(3))) void*)(lb + 512 * 8), 16, 0, 0); \
        __builtin_amdgcn_global_load_lds(                                     \
            (const __attribute__((address_space(1))) void*)(Bhi + boff + (koff)), \
            (__attribute__((address_space(3))) void*)(lb + 1024 * 8), 16, 0, 0); \
        __builtin_amdgcn_global_load_lds(                                     \
            (const __attribute__((address_space(1))) void*)(Blo + boff + (koff)), \
            (__attribute__((address_space(3))) void*)(lb + 1536 * 8), 16, 0, 0); \
    }

    f32x4 acc[2][4];
#pragma unroll
    for (int i = 0; i < 2; i++)
#pragma unroll
        for (int j = 0; j < 4; j++)
            acc[i][j] = (f32x4){0.f, 0.f, 0.f, 0.f};

    STAGE8(0, 0)
    int buf = 0;
    const int NT = K >> 5;
    for (int t = 0; t < NT; t++) {
        __syncthreads();                 // buf staged (vmcnt drain) + prev reads done
        if (t + 1 < NT) STAGE8(buf ^ 1, (t + 1) << 5)

        const u16* Lb = (const u16*)smem + buf * (2048 * 8);
        bf16x8 ah[2], al[2], bh[4], bl[4];
#pragma unroll
        for (int i = 0; i < 2; i++) {
            const int off = (wy * 32 + i * 16 + l15) * 32 + cA;
            ah[i] = *(const bf16x8*)(Lb + off);
            al[i] = *(const bf16x8*)(Lb + 512 * 8 + off);
        }
#pragma unroll
        for (int j = 0; j < 4; j++) {
            const int off = (wx * 64 + j * 16 + l15) * 32 + cA;
            bh[j] = *(const bf16x8*)(Lb + 1024 * 8 + off);
            bl[j] = *(const bf16x8*)(Lb + 1536 * 8 + off);
        }

#pragma unroll
        for (int i = 0; i < 2; i++)
#pragma unroll
            for (int j = 0; j < 4; j++) {
                acc[i][j] = __builtin_amdgcn_mfma_f32_16x16x32_bf16(
                    ah[i], bh[j], acc[i][j], 0, 0, 0);
                acc[i][j] = __builtin_amdgcn_mfma_f32_16x16x32_bf16(
                    ah[i], bl[j], acc[i][j], 0, 0, 0);
                acc[i][j] = __builtin_amdgcn_mfma_f32_16x16x32_bf16(
                    al[i], bh[j], acc[i][j], 0, 0, 0);
            }
        buf ^= 1;
    }
#undef STAGE8

    const int mBase = (int)mTile + wy * 32;
    const int nBase = (int)nTile + wx * 64;
#pragma unroll
    for (int i = 0; i < 2; i++) {
#pragma unroll
        for (int j = 0; j < 4; j++) {
            const int n = nBase + j * 16 + l15;
            const float bv = BIAS ? bias[n] : 0.0f;
#pragma unroll
            for (int r = 0; r < 4; r++) {
                const int m = mBase + i * 16 + quad * 4 + r;
                float v = acc[i][j][r] + bv;
                if (RELU) v = fmaxf(v, 0.0f);
                const long o = cOff + (long)m * ldc + n;
                if (WF32) C[o] = v;
                if (WSPLIT) {
                    u16 h, l;
                    splitf(v, h, l);
                    Chi[o] = h;
                    Clo[o] = l;
                }
            }
        }
    }
}

// ---------------------------------------------------------------------------
// 4-wave split-bf16 GEMM (kept for KXT, MI=1: tile 32x128). LDS structure +
// XCD swizzle. Optional zero-sweep of the per-layer mask scratch
// (rowmax/rowcnt/colcnt/tmax) folded into the prologue — kernel-boundary
// ordering guarantees visibility to smax/sextract which launch after.
// ---------------------------------------------------------------------------
template <int MI, int BIAS, int RELU, int WF32, int WSPLIT>
__global__ __launch_bounds__(256, 2) void mgemm_k(
    const u16* __restrict__ Ahi, const u16* __restrict__ Alo,
    const u16* __restrict__ Bhi, const u16* __restrict__ Blo,
    float* __restrict__ C, u16* __restrict__ Chi, u16* __restrict__ Clo,
    const float* __restrict__ bias,
    int M, int N, int K, int lda, int ldb, int ldc,
    long sAoff, long sBoff, long sCoff,
    unsigned* __restrict__ zbase, int zn)
{
    constexpr int ACH = MI * 128;        // 16B chunks per A stream per BK-tile
    constexpr int TOT = 2 * ACH + 1024;  // chunks per buffer (Ahi|Alo|Bhi|Blo)
    __shared__ __align__(16) u16 smem[2 * TOT * 8];

    const int bz = blockIdx.z;
    Ahi += bz * sAoff;  Alo += bz * sAoff;
    Bhi += bz * sBoff;  Blo += bz * sBoff;
    const long cOff = (long)bz * sCoff;

    const int gx = gridDim.x, nwg = gx * gridDim.y;
    int lin = blockIdx.y * gx + blockIdx.x;
    lin = (lin & 7) * (nwg >> 3) + (lin >> 3);
    const int bxs = lin % gx, bys = lin / gx;

    const int tid  = threadIdx.x;

    // zero-sweep (only KXT passes zbase != null)
    if (zbase) {
        const int gtid = (blockIdx.y * gx + blockIdx.x) * 256 + tid;
        const int gstr = nwg * 256;
        for (int i = gtid; i < zn; i += gstr) zbase[i] = 0u;
    }

    const int wave = tid >> 6, lane = tid & 63;
    const int quad = lane >> 4, l15 = lane & 15;
    const int wy = wave >> 1, wx = wave & 1;
    const long mTile = (long)bys * (MI * 32);
    const long nTile = (long)bxs * 128;
    const int mBase = (int)mTile + wy * (MI * 16);
    const int nBase = (int)nTile + wx * 64;

    const int fsw = (l15 & 3) ^ ((l15 >> 2) & 3);
    const int cA  = (quad ^ fsw) * 8;

#define STAGE(bufi, koff)                                                     \
    {                                                                         \
        _Pragma("unroll")                                                     \
        for (int s = 0; s < TOT / 256; s++) {                                 \
            const int idx = s * 256 + tid;                                    \
            const u16* sp;  long rowb;  int ldx;  int rel;                    \
            if (idx < ACH)                { sp = Ahi; rel = idx;               rowb = 0; ldx = lda; } \
            else if (idx < 2 * ACH)       { sp = Alo; rel = idx - ACH;         rowb = 0; ldx = lda; } \
            else if (idx < 2 * ACH + 512) { sp = Bhi; rel = idx - 2 * ACH;     rowb = 1; ldx = ldb; } \
            else                          { sp = Blo; rel = idx - 2*ACH - 512; rowb = 1; ldx = ldb; } \
            const long rb = rowb ? nTile : mTile;                             \
            const int r = rel >> 2;                                           \
            const int c = (rel & 3) ^ ((r & 3) ^ ((r >> 2) & 3));             \
            const u16* g = sp + (rb + r) * (long)ldx + (koff) + c * 8;        \
            u16* lp = (u16*)smem + (bufi) * (TOT * 8) + idx * 8;              \
            __builtin_amdgcn_global_load_lds(                                 \
                (const __attribute__((address_space(1))) void*)g,             \
                (__attribute__((address_space(3))) void*)lp, 16, 0, 0);       \
        }                                                                     \
    }

    f32x4 acc[MI][4];
#pragma unroll
    for (int i = 0; i < MI; i++)
#pragma unroll
        for (int j = 0; j < 4; j++)
            acc[i][j] = (f32x4){0.f, 0.f, 0.f, 0.f};

    STAGE(0, 0)
    int buf = 0;
    const int NT = K >> 5;
    for (int t = 0; t < NT; t++) {
        __syncthreads();
        if (t + 1 < NT) STAGE(buf ^ 1, (t + 1) << 5)

        const u16* Lb = (const u16*)smem + buf * (TOT * 8);
        bf16x8 ah[MI], al[MI], bh[4], bl[4];
#pragma unroll
        for (int i = 0; i < MI; i++) {
            const int off = (wy * (MI * 16) + i * 16 + l15) * 32 + cA;
            ah[i] = *(const bf16x8*)(Lb + off);
            al[i] = *(const bf16x8*)(Lb + ACH * 8 + off);
        }
#pragma unroll
        for (int j = 0; j < 4; j++) {
            const int off = (wx * 64 + j * 16 + l15) * 32 + cA;
            bh[j] = *(const bf16x8*)(Lb + 2 * ACH * 8 + off);
            bl[j] = *(const bf16x8*)(Lb + 2 * ACH * 8 + 512 * 8 + off);
        }

#pragma unroll
        for (int i = 0; i < MI; i++)
#pragma unroll
            for (int j = 0; j < 4; j++) {
                acc[i][j] = __builtin_amdgcn_mfma_f32_16x16x32_bf16(
                    ah[i], bh[j], acc[i][j], 0, 0, 0);
                acc[i][j] = __builtin_amdgcn_mfma_f32_16x16x32_bf16(
                    ah[i], bl[j], acc[i][j], 0, 0, 0);
                acc[i][j] = __builtin_amdgcn_mfma_f32_16x16x32_bf16(
                    al[i], bh[j], acc[i][j], 0, 0, 0);
            }
        buf ^= 1;
    }
#undef STAGE

#pragma unroll
    for (int i = 0; i < MI; i++) {
#pragma unroll
        for (int j = 0; j < 4; j++) {
            const int n = nBase + j * 16 + l15;
            const float bv = BIAS ? bias[n] : 0.0f;
#pragma unroll
            for (int r = 0; r < 4; r++) {
                const int m = mBase + i * 16 + quad * 4 + r;
                float v = acc[i][j][r] + bv;
                if (RELU) v = fmaxf(v, 0.0f);
                const long o = cOff + (long)m * ldc + n;
                if (WF32) C[o] = v;
                if (WSPLIT) {
                    u16 h, l;
                    splitf(v, h, l);
                    Chi[o] = h;
                    Clo[o] = l;
                }
            }
        }
    }
}

// ---------------------------------------------------------------------------
// Fused mask path, pass A: per-head Gram tile S = G G^T via one-shot LDS
// staging. MFMA order (s{i{j{hh,hl,lh}}}) IDENTICAL to sextract_k -> same
// bits. Publishes per-tile per-row maxima (tmaxU) for pass-B early exit.
// ---------------------------------------------------------------------------
__global__ __launch_bounds__(256, 2) void smax_k(
    const u16* __restrict__ Ghi, const u16* __restrict__ Glo,
    unsigned* __restrict__ rowmaxU, unsigned* __restrict__ tmaxU)
{
    __shared__ __align__(16) u16 gs[4096 * 8];   // 64 KB: Ahi|Alo|Bhi|Blo
    const int h = blockIdx.z;
    const int lda = HH * QQ;
    const u16* Gh = Ghi + h * QQ;
    const u16* Gl = Glo + h * QQ;

    const int gx = gridDim.x, nwg = gx * gridDim.y;   // 16, 256
    int lin = blockIdx.y * gx + blockIdx.x;
    lin = (lin & 7) * (nwg >> 3) + (lin >> 3);
    const int bxs = lin % gx, bys = lin / gx;

    const int tid  = threadIdx.x;
    const int wave = tid >> 6, lane = tid & 63;
    const int quad = lane >> 4, l15 = lane & 15;
    const int wy = wave >> 1, wx = wave & 1;
    const int rT = bys * 128, cT = bxs * 128;
    const int rB = rT + wy * 64;

#define SSTG(src, rowbase, dstbase)                                           \
    _Pragma("unroll")                                                         \
    for (int it = 0; it < 4; it++) {                                          \
        const int idx = it * 256 + tid;                                       \
        const int r = idx >> 3;                                               \
        const int c = (idx & 7) ^ (r & 7);                                    \
        __builtin_amdgcn_global_load_lds(                                     \
            (const __attribute__((address_space(1))) void*)(src + (long)((rowbase) + r) * lda + c * 8), \
            (__attribute__((address_space(3))) void*)((u16*)gs + (dstbase) + idx * 8), 16, 0, 0); \
    }
    SSTG(Gh, rT, 0)
    SSTG(Gl, rT, 8192)
    SSTG(Gh, cT, 16384)
    SSTG(Gl, cT, 24576)
#undef SSTG
    __syncthreads();

    bf16x8 ah[2][4], al[2][4], bh[2][4], bl[2][4];
#pragma unroll
    for (int s = 0; s < 2; s++) {
#pragma unroll
        for (int i = 0; i < 4; i++) {
            const int ra = wy * 64 + i * 16 + l15;
            const int ca = ((s * 4 + quad) ^ (ra & 7)) * 8;
            ah[s][i] = *(const bf16x8*)(gs + ra * 64 + ca);
            al[s][i] = *(const bf16x8*)(gs + 8192 + ra * 64 + ca);
            const int rb = wx * 64 + i * 16 + l15;
            const int cb = ((s * 4 + quad) ^ (rb & 7)) * 8;
            bh[s][i] = *(const bf16x8*)(gs + 16384 + rb * 64 + cb);
            bl[s][i] = *(const bf16x8*)(gs + 24576 + rb * 64 + cb);
        }
    }

    f32x4 acc[4][4];
#pragma unroll
    for (int i = 0; i < 4; i++)
#pragma unroll
        for (int j = 0; j < 4; j++)
            acc[i][j] = (f32x4){0.f, 0.f, 0.f, 0.f};

#pragma unroll
    for (int s = 0; s < 2; s++)
#pragma unroll
        for (int i = 0; i < 4; i++)
#pragma unroll
            for (int j = 0; j < 4; j++) {
                acc[i][j] = __builtin_amdgcn_mfma_f32_16x16x32_bf16(ah[s][i], bh[s][j], acc[i][j], 0, 0, 0);
                acc[i][j] = __builtin_amdgcn_mfma_f32_16x16x32_bf16(ah[s][i], bl[s][j], acc[i][j], 0, 0, 0);
                acc[i][j] = __builtin_amdgcn_mfma_f32_16x16x32_bf16(al[s][i], bh[s][j], acc[i][j], 0, 0, 0);
            }

    const unsigned tBase = (unsigned)((((h << 4) + bys) << 4) + bxs) * 128u;
#pragma unroll
    for (int i = 0; i < 4; i++)
#pragma unroll
        for (int r = 0; r < 4; r++) {
            float mx = acc[i][0][r];
#pragma unroll
            for (int j = 1; j < 4; j++) mx = fmaxf(mx, acc[i][j][r]);
#pragma unroll
            for (int off = 1; off < 16; off <<= 1)
                mx = fmaxf(mx, __shfl_xor(mx, off, 64));
            if (l15 == 0) {
                const int lr = wy * 64 + i * 16 + quad * 4 + r;
                const unsigned mv = mapf(mx);
                atomicMax(&rowmaxU[h * NN + rT + lr], mv);
                atomicMax(&tmaxU[tBase + lr], mv);
            }
        }
}

// ---------------------------------------------------------------------------
// Fused mask path, pass B: EARLY-EXIT via tmaxU (exact bit-level test), else
// recompute IDENTICAL S tile, threshold, count, emit. Column counts for the
// CSR build are aggregated in a 128-slot LDS histogram (block's column window
// is cT..cT+127) and flushed with <=128 global atomics per emitting block.
// ---------------------------------------------------------------------------
__global__ __launch_bounds__(256) void sextract_k(
    const u16* __restrict__ Ghi, const u16* __restrict__ Glo,
    const unsigned* __restrict__ rowmaxU, const unsigned* __restrict__ tmaxU,
    int* __restrict__ rowcnt, unsigned* __restrict__ colcnt,
    unsigned int* __restrict__ entries, int* __restrict__ counter)
{
    const int h = blockIdx.z;
    const u16* Ah = Ghi + h * QQ;
    const u16* Al = Glo + h * QQ;
    const int lda = HH * QQ;

    const int gx = gridDim.x, nwg = gx * gridDim.y;
    int lin = blockIdx.y * gx + blockIdx.x;
    lin = (lin & 7) * (nwg >> 3) + (lin >> 3);
    const int bxs = lin % gx, bys = lin / gx;

    const int tid  = threadIdx.x;
    const int wave = tid >> 6, lane = tid & 63;
    const int quad = lane >> 4, l15 = lane & 15;
    const int wy = wave >> 1, wx = wave & 1;
    const int rB = bys * 128 + wy * 64;
    const int cT = bxs * 128;
    const int cB = cT + wx * 64;

    __shared__ float thrS[128];
    __shared__ int chist[128];
    __shared__ unsigned lbuf[LCAP];
    __shared__ int lcnt, gbase, anyf;
    if (tid == 0) { lcnt = 0; anyf = 0; }
    if (tid < 128) {
        chist[tid] = 0;
        float mx = unmapf(rowmaxU[h * NN + bys * 128 + tid]);
        float thr = (fabsf(mx) > 0.5f) ? mx - 0.5f : 3.402823466e38f;
        thrS[tid] = thr;
        float tm = unmapf(tmaxU[(unsigned)((((h << 4) + bys) << 4) + bxs) * 128u + tid]);
        if (tm >= thr) atomicAdd(&anyf, 1);
    }
    __syncthreads();
    if (anyf == 0) return;   // tile provably empty (exact bit-level test)

    bf16x8 ah[2][4], al[2][4], bh[2][4], bl[2][4];
#pragma unroll
    for (int s = 0; s < 2; s++) {
        const int kk = s * 32 + quad * 8;
#pragma unroll
        for (int i = 0; i < 4; i++) {
            long ar = (long)(rB + i * 16 + l15) * lda + kk;
            ah[s][i] = *(const bf16x8*)(Ah + ar);
            al[s][i] = *(const bf16x8*)(Al + ar);
            long br = (long)(cB + i * 16 + l15) * lda + kk;
            bh[s][i] = *(const bf16x8*)(Ah + br);
            bl[s][i] = *(const bf16x8*)(Al + br);
        }
    }

    f32x4 acc[4][4];
#pragma unroll
    for (int i = 0; i < 4; i++)
#pragma unroll
        for (int j = 0; j < 4; j++)
            acc[i][j] = (f32x4){0.f, 0.f, 0.f, 0.f};

#pragma unroll
    for (int s = 0; s < 2; s++)
#pragma unroll
        for (int i = 0; i < 4; i++)
#pragma unroll
            for (int j = 0; j < 4; j++) {
                acc[i][j] = __builtin_amdgcn_mfma_f32_16x16x32_bf16(ah[s][i], bh[s][j], acc[i][j], 0, 0, 0);
                acc[i][j] = __builtin_amdgcn_mfma_f32_16x16x32_bf16(ah[s][i], bl[s][j], acc[i][j], 0, 0, 0);
                acc[i][j] = __builtin_amdgcn_mfma_f32_16x16x32_bf16(al[s][i], bh[s][j], acc[i][j], 0, 0, 0);
            }

#pragma unroll
    for (int i = 0; i < 4; i++) {
#pragma unroll
        for (int r = 0; r < 4; r++) {
            const int lr  = wy * 64 + i * 16 + quad * 4 + r;
            const int row = h * NN + rB + i * 16 + quad * 4 + r;
            const float thr = thrS[lr];

            int c = 0;
#pragma unroll
            for (int j = 0; j < 4; j++) c += (acc[i][j][r] >= thr) ? 1 : 0;
            int cs = c;
#pragma unroll
            for (int off = 1; off < 16; off <<= 1) cs += __shfl_xor(cs, off, 64);
            if (l15 == 0 && cs > 0) atomicAdd(&rowcnt[row], cs);

#pragma unroll
            for (int j = 0; j < 4; j++) {
                if (acc[i][j][r] >= thr) {
                    const unsigned m = (unsigned)(cB + j * 16 + l15);
                    unsigned ent = ((unsigned)row << 11) | m;
                    atomicAdd(&chist[m & 127], 1);
                    int s2 = atomicAdd(&lcnt, 1);
                    if (s2 < LCAP) {
                        lbuf[s2] = ent;
                    } else {
                        unsigned p = (unsigned)atomicAdd(counter, 1);
                        if (p < ENTRY_CAP) entries[p] = ent;
                    }
                }
            }
        }
    }

    __syncthreads();
    // aggregated colcnt flush (<=128 global atomics per emitting block)
    if (tid < 128) {
        int hc = chist[tid];
        if (hc > 0) atomicAdd(&colcnt[cT + tid], (unsigned)hc);
    }
    int n = lcnt;
    if (n > LCAP) n = LCAP;
    if (n > 0) {
        if (tid == 0) gbase = atomicAdd(counter, n);
        __syncthreads();
        for (int i2 = tid; i2 < n; i2 += 256) {
            unsigned p = (unsigned)(gbase + i2);
            if (p < ENTRY_CAP) entries[p] = lbuf[i2];
        }
    }
}

// ---------------------------------------------------------------------------
// Parallel CSR build: scan (1 block: 2048-wide exclusive scan of colcnt ->
// colOff + cursor init) + two-level scatter (per-block LDS histogram ->
// one colCur reservation atomic per distinct column per block -> LDS-cursor
// placement). Avoids per-entry device-scope atomic contention.
// ---------------------------------------------------------------------------
__global__ __launch_bounds__(256) void scan_k(
    const unsigned* __restrict__ colcnt, int* __restrict__ colOff,
    int* __restrict__ colCur)
{
    __shared__ int part[256];
    const int t = threadIdx.x;
    int e[8];
    int s = 0;
#pragma unroll
    for (int i = 0; i < 8; i++) { e[i] = s; s += (int)colcnt[t * 8 + i]; }
    part[t] = s;
    __syncthreads();
    for (int off = 1; off < 256; off <<= 1) {
        int x = (t >= off) ? part[t - off] : 0;
        __syncthreads();
        part[t] += x;
        __syncthreads();
    }
    int base = (t > 0) ? part[t - 1] : 0;
#pragma unroll
    for (int i = 0; i < 8; i++) {
        colOff[t * 8 + i] = base + e[i];
        colCur[t * 8 + i] = base + e[i];
    }
    if (t == 255) colOff[NN] = part[255];
}

__global__ __launch_bounds__(256) void scatter_k(
    const unsigned int* __restrict__ entries, const int* __restrict__ counter,
    unsigned int* __restrict__ csr, int* __restrict__ colCur)
{
    __shared__ int hist[NN];   // 8 KB: per-chunk histogram, then local cursor
    __shared__ int base[NN];   // 8 KB: reserved global base per column
    int cnt = *counter;
    if (cnt > ENTRY_CAP) cnt = ENTRY_CAP;
    const int nb = gridDim.x;
    const int chunk = (cnt + nb - 1) / nb;
    const int s0 = blockIdx.x * chunk;
    int s1 = s0 + chunk;
    if (s1 > cnt) s1 = cnt;
    if (s0 >= s1) return;

    for (int i = threadIdx.x; i < NN; i += 256) hist[i] = 0;
    __syncthreads();
    for (int i = s0 + threadIdx.x; i < s1; i += 256)
        atomicAdd(&hist[entries[i] & 2047], 1);
    __syncthreads();
    for (int i = threadIdx.x; i < NN; i += 256) {
        int hcount = hist[i];
        base[i] = (hcount > 0) ? atomicAdd(&colCur[i], hcount) : 0;
        hist[i] = 0;   // reuse as local cursor
    }
    __syncthreads();
    for (int i = s0 + threadIdx.x; i < s1; i += 256) {
        unsigned v = entries[i];
        int m = v & 2047;
        int off = atomicAdd(&hist[m], 1);
        csr[base[m] + off] = v;
    }
}

// ---------------------------------------------------------------------------
// split / splitall (x2 work/thread + counters zero; hoisted out of the loop)
// / splitc / apply(inline wrecip) / ff2red(+attnT writeback) / transpose
// ---------------------------------------------------------------------------
__global__ __launch_bounds__(256) void split_k(
    const float* __restrict__ src, u16* __restrict__ hi, u16* __restrict__ lo)
{
    int i = blockIdx.x * 256 + threadIdx.x;
    float4 v = ((const float4*)src)[i];
    ushort4 hv, lv;
    splitf(v.x, hv.x, lv.x);
    splitf(v.y, hv.y, lv.y);
    splitf(v.z, hv.z, lv.z);
    splitf(v.w, hv.w, lv.w);
    ((ushort4*)hi)[i] = hv;
    ((ushort4*)lo)[i] = lv;
}

// initial split that also seeds attnT = X^T
__global__ __launch_bounds__(256) void splitc_k(
    const float* __restrict__ src, u16* __restrict__ hi, u16* __restrict__ lo,
    float* __restrict__ cpy)
{
    int i = blockIdx.x * 256 + threadIdx.x;
    float4 v = ((const float4*)src)[i];
    ((float4*)cpy)[i] = v;
    ushort4 hv, lv;
    splitf(v.x, hv.x, lv.x);
    splitf(v.y, hv.y, lv.y);
    splitf(v.z, hv.z, lv.z);
    splitf(v.w, hv.w, lv.w);
    ((ushort4*)hi)[i] = hv;
    ((ushort4*)lo)[i] = lv;
}

// one-shot split of ALL layers' weights; 2 coalesced sweeps per thread
// (region boundaries are multiples of 256 float4) + counters zero.
__global__ __launch_bounds__(256) void splitall_k(
    const float* __restrict__ K_, const float* __restrict__ V_,
    const float* __restrict__ W1_, const float* __restrict__ W2_,
    u16* __restrict__ KhiA, u16* __restrict__ KloA,
    u16* __restrict__ VhiA, u16* __restrict__ VloA,
    u16* __restrict__ W1hiA, u16* __restrict__ W1loA,
    u16* __restrict__ W2hiA, u16* __restrict__ W2loA,
    int* __restrict__ counters)
{
    if (blockIdx.x == 0 && threadIdx.x < LL) counters[threadIdx.x] = 0;
    const int li  = blockIdx.x / 1600;
    const int sub = blockIdx.x % 1600;
#pragma unroll
    for (int jj = 0; jj < 2; jj++) {
        int i = sub * 512 + jj * 256 + threadIdx.x;  // float4 idx in layer
        const float* s;
        u16 *h, *l;
        int off;
        if (i < 32768) {
            s = K_ + (long)li * 131072;
            h = KhiA + (long)li * 131072;  l = KloA + (long)li * 131072;
            off = i;
        } else if (i < 294912) {
            s = V_ + (long)li * 1048576;
            h = VhiA + (long)li * 1048576; l = VloA + (long)li * 1048576;
            off = i - 32768;
        } else if (i < 557056) {
            s = W1_ + (long)li * 1048576;
            h = W1hiA + (long)li * 1048576; l = W1loA + (long)li * 1048576;
            off = i - 294912;
        } else {
            s = W2_ + (long)li * 1048576;
            h = W2hiA + (long)li * 1048576; l = W2loA + (long)li * 1048576;
            off = i - 557056;
        }
        float4 v = ((const float4*)s)[off];
        ushort4 hv, lv;
        splitf(v.x, hv.x, lv.x);
        splitf(v.y, hv.y, lv.y);
        splitf(v.z, hv.z, lv.z);
        splitf(v.w, hv.w, lv.w);
        ((ushort4*)h)[off] = hv;
        ((ushort4*)l)[off] = lv;
    }
}

__global__ __launch_bounds__(256) void apply_k(
    const unsigned int* __restrict__ csr, const int* __restrict__ colOff,
    const unsigned* __restrict__ rowmaxU, const int* __restrict__ rowcnt,
    const float* __restrict__ Yt, float* __restrict__ attnT)
{
    const int total = colOff[NN];
    const int tid = threadIdx.x;

    for (int base = blockIdx.x * CHUNK; base < total;
         base += gridDim.x * CHUNK) {
        int end = base + CHUNK;
        if (end > total) end = total;

        float a0 = 0.0f, a1 = 0.0f;
        int curM = -1;
        for (int e = base; e < end; e++) {
            unsigned v = csr[e];
            int m = v & 2047;
            int row = (int)(v >> 11);
            if (m != curM) {
                if (curM >= 0) {
                    atomicAdd(&attnT[(long)curM * DD + tid], a0);
                    atomicAdd(&attnT[(long)curM * DD + tid + 256], a1);
                }
                curM = m;
                a0 = a1 = 0.0f;
            }
            float mx = unmapf(rowmaxU[row]);
            float w = (fabsf(mx) > 0.5f)
                          ? 1.0f / fmaxf((float)rowcnt[row], 1.0f) : 0.0f;
            const float* y = Yt + (long)row * DD;
            a0 += w * y[tid];
            a1 += w * y[tid + 256];
        }
        if (curM >= 0) {
            atomicAdd(&attnT[(long)curM * DD + tid], a0);
            atomicAdd(&attnT[(long)curM * DD + tid + 256], a1);
        }
    }
}

__global__ __launch_bounds__(256) void ff2red_k(
    const float* __restrict__ Cpart, const float* __restrict__ b2,
    float* __restrict__ attnT, float* __restrict__ Xn,
    u16* __restrict__ Xhi, u16* __restrict__ Xlo)
{
    int i = blockIdx.x * 256 + threadIdx.x;
    float4 v0 = ((const float4*)(Cpart))[i];
    float4 v1 = ((const float4*)(Cpart + 1048576))[i];
    float4 v2 = ((const float4*)(Cpart + 2097152))[i];
    float4 v3 = ((const float4*)(Cpart + 3145728))[i];
    float4 bv = ((const float4*)b2)[i & 127];
    float4 rv = ((const float4*)attnT)[i];
    float4 o;
    o.x = v0.x + v1.x + v2.x + v3.x + bv.x + rv.x;
    o.y = v0.y + v1.y + v2.y + v3.y + bv.y + rv.y;
    o.z = v0.z + v1.z + v2.z + v3.z + bv.z + rv.z;
    o.w = v0.w + v1.w + v2.w + v3.w + bv.w + rv.w;
    ((float4*)Xn)[i] = o;
    ((float4*)attnT)[i] = o;           // seed next layer's residual base
    ushort4 hv, lv;
    splitf(o.x, hv.x, lv.x);
    splitf(o.y, hv.y, lv.y);
    splitf(o.z, hv.z, lv.z);
    splitf(o.w, hv.w, lv.w);
    ((ushort4*)Xhi)[i] = hv;
    ((ushort4*)Xlo)[i] = lv;
}

__global__ __launch_bounds__(256) void transpose_k(
    const float* __restrict__ src, float* __restrict__ dst, int R, int C)
{
    __shared__ float t[32][33];
    int tx = threadIdx.x & 31, ty = threadIdx.x >> 5;
    int c0 = blockIdx.x * 32, r0 = blockIdx.y * 32;
#pragma unroll
    for (int k = 0; k < 4; k++)
        t[ty + 8 * k][tx] = src[(long)(r0 + ty + 8 * k) * C + c0 + tx];
    __syncthreads();
#pragma unroll
    for (int k = 0; k < 4; k++)
        dst[(long)(c0 + ty + 8 * k) * R + r0 + tx] = t[tx][ty + 8 * k];
}

// ---------------------------------------------------------------------------
// Workspace layout (~193 MB < 256 MiB workspace).
// ---------------------------------------------------------------------------
extern "C" void kernel_launch(void* const* d_in, const int* in_sizes, int n_in,
                              void* d_out, int out_size, void* d_ws, size_t ws_size,
                              hipStream_t stream)
{
    const float* X0 = (const float*)d_in[0];
    const float* Kw = (const float*)d_in[1];
    const float* Vw = (const float*)d_in[2];
    const float* W1 = (const float*)d_in[3];
    const float* b1 = (const float*)d_in[4];
    const float* W2 = (const float*)d_in[5];
    const float* b2 = (const float*)d_in[6];
    float* out = (float*)d_out;

    float* R0    = (float*)d_ws;
    float* Yt    = R0;                       // 4,194,304  [H,NN,DD] fp32
    u16*   ff1hi = (u16*)(R0 + 4194304);
    u16*   ff1lo = (u16*)(R0 + 6291456);
    float* Cpart = R0 + 8388608;             // 4,194,304
    float* attnT = R0 + 12582912;            // 1,048,576

    float* ext = R0 + 13631488;
    u16* KXThi = (u16*)ext;                  // 262,144 words
    u16* KXTlo = (u16*)(ext + 262144);
    float* XbufA = ext + 524288;             // 1,048,576
    float* XbufB = ext + 1572864;            // 1,048,576
    u16* Xhi  = (u16*)(ext + 2621440);       // 524,288 words
    u16* Xlo  = (u16*)(ext + 3145728);
    u16* athi = (u16*)(ext + 3670016);
    u16* atlo = (u16*)(ext + 4194304);       // (ext+4718592 .. ext+8003583 free)
    unsigned int* entries = (unsigned int*)(ext + 8003584);  // 131,072
    unsigned int* csr     = (unsigned int*)(ext + 8134656);  // 131,072
    int* colOff   = (int*)(ext + 8265728);   // 2,112
    int* counters = (int*)(ext + 8267840);   // 64
    // contiguous zero region (ZWORDS = 149,504 u32):
    unsigned* rowmaxU = (unsigned*)(ext + 8267904);  // 8,192
    int* rowcnt   = (int*)(ext + 8276096);           // 8,192
    unsigned* colcnt = (unsigned*)(ext + 8284288);   // 2,048
    unsigned* tmaxU = (unsigned*)(ext + 8286336);    // 131,072
    int* colCur   = (int*)(ext + 8417408);           // 2,048
    // all-layer weight splits (u16), 104.9 MB:
    u16* wbase = (u16*)(ext + 8419456);
    u16* KhiA  = wbase;                         // 8 x 131,072
    u16* KloA  = wbase + 1048576;
    u16* VhiA  = wbase + 2097152;               // 8 x 1,048,576
    u16* VloA  = wbase + 10485760;
    u16* W1hiA = wbase + 18874368;
    u16* W1loA = wbase + 27262976;
    u16* W2hiA = wbase + 35651584;
    u16* W2loA = wbase + 44040192;              // ends at 52,428,800 u16

    // all-layer weight split (hoisted) + counters zero
    splitall_k<<<dim3(LL * 1600), 256, 0, stream>>>(
        Kw, Vw, W1, W2, KhiA, KloA, VhiA, VloA, W1hiA, W1loA, W2hiA, W2loA,
        counters);

    // XT0 = X0^T [N, D]; split to bf16 hi/lo and seed attnT = XT0
    transpose_k<<<dim3(NN / 32, DD / 32), 256, 0, stream>>>(X0, XbufA, DD, NN);
    splitc_k<<<dim3(1024), 256, 0, stream>>>(XbufA, Xhi, Xlo, attnT);

    float* Xc = XbufA;
    for (int li = 0; li < LL; li++) {
        float* Xn = (li & 1) ? XbufA : XbufB;
        u16* Khi = KhiA + (long)li * 131072;
        u16* Klo = KloA + (long)li * 131072;
        u16* Vhi = VhiA + (long)li * 1048576;
        u16* Vlo = VloA + (long)li * 1048576;
        u16* W1hi = W1hiA + (long)li * 1048576;
        u16* W1lo = W1loA + (long)li * 1048576;
        u16* W2hi = W2hiA + (long)li * 1048576;
        u16* W2lo = W2loA + (long)li * 1048576;

        // 1) KXT = XT @ Kw^T  [2048, 256], K=512 -> hi/lo. MI=1: 128 blocks.
        //    Prologue zero-sweeps rowmax/rowcnt/colcnt/tmax for this layer.
        mgemm_k<1, 0, 0, 0, 1><<<dim3(2, 64, 1), 256, 0, stream>>>(
            Xhi, Xlo, Khi, Klo, nullptr, KXThi, KXTlo, nullptr,
            NN, HH * QQ, DD, DD, DD, HH * QQ, 0, 0, 0,
            rowmaxU, ZWORDS);

        // 2) fused mask path: no S materialization
        smax_k<<<dim3(16, 16, HH), 256, 0, stream>>>(KXThi, KXTlo, rowmaxU, tmaxU);
        sextract_k<<<dim3(16, 16, HH), 256, 0, stream>>>(
            KXThi, KXTlo, rowmaxU, tmaxU, rowcnt, colcnt, entries, counters + li);
        scan_k<<<dim3(1), 256, 0, stream>>>(colcnt, colOff, colCur);
        scatter_k<<<dim3(64), 256, 0, stream>>>(entries, counters + li, csr, colCur);

        // 4) Yt_h = XT @ V_h^T  [NN, DD] fp32, batch H. 8-wave: 64 blk/head.
        mgemm8_k<0, 0, 1, 0><<<dim3(4, 16, HH), 512, 0, stream>>>(
            Xhi, Xlo, Vhi, Vlo, Yt, nullptr, nullptr, nullptr,
            DD, DD, DD, DD, 0, (long)DD * DD, (long)NN * DD);

        // 5) attnT (= XT residual) += sparse combine; split for FF1 input
        apply_k<<<dim3(APPLY_BLOCKS), 256, 0, stream>>>(
            csr, colOff, rowmaxU, rowcnt, Yt, attnT);
        split_k<<<dim3(1024), 256, 0, stream>>>(attnT, athi, atlo);

        // 6) ff1 = relu(attnT @ W1^T + b1)  [NN, DFF] -> hi/lo. 256 blocks.
        mgemm8_k<1, 1, 0, 1><<<dim3(16, 16, 1), 512, 0, stream>>>(
            athi, atlo, W1hi, W1lo, nullptr, ff1hi, ff1lo,
            b1 + (long)li * DFFC,
            DD, DD, DD, DFFC, 0, 0, 0);

        // 7) FF2 split-K=4: 64 blocks x 4.
        mgemm8_k<0, 0, 1, 0><<<dim3(4, 16, 4), 512, 0, stream>>>(
            ff1hi, ff1lo, W2hi, W2lo, Cpart, nullptr, nullptr, nullptr,
            512, DFFC, DFFC, DD, 512, 512, (long)NN * DD);
        ff2red_k<<<dim3(1024), 256, 0, stream>>>(
            Cpart, b2 + (long)li * DD, attnT, Xn, Xhi, Xlo);

        Xc = Xn;
    }

    // out = XT_final^T  [D, N]
    transpose_k<<<dim3(DD / 32, NN / 32), 256, 0, stream>>>(Xc, out, NN, DD);
}

// Round 9
// 1226.103 us; speedup vs baseline: 1.8161x; 1.0004x over previous
//
#include <hip/hip_runtime.h>

// Problem constants
#define LL   8
#define HH   4
#define QQ   64
#define DD   512
#define NN   2048
#define DFFC 2048
#define ENTRY_CAP (1 << 17)
#define CHUNK 8
#define APPLY_BLOCKS 2048
#define LCAP 2048   // per-block LDS entry staging capacity
#define ZWORDS 149504  // rowmaxU(8192)+rowcnt(8192)+colcnt(2048)+tmaxU(131072)

typedef short     bf16x8 __attribute__((ext_vector_type(8)));  // 8 bf16 = 4 VGPR
typedef float     f32x4  __attribute__((ext_vector_type(4)));  // MFMA C/D frag
typedef unsigned short u16;

// fp32 -> (hi, lo) bf16 split, RNE. x ~= hi + lo with ~16-bit mantissa coverage.
__device__ inline void splitf(float v, u16& h, u16& l)
{
    unsigned u  = __float_as_uint(v);
    unsigned uh = u + (0x7FFFu + ((u >> 16) & 1u));
    h = (u16)(uh >> 16);
    float fh = __uint_as_float(((unsigned)h) << 16);
    float r  = v - fh;
    unsigned ur = __float_as_uint(r);
    unsigned ul = ur + (0x7FFFu + ((ur >> 16) & 1u));
    l = (u16)(ul >> 16);
}

// Monotone fp32 <-> uint mapping for atomicMax on floats (no NaNs in data).
__device__ inline unsigned mapf(float f)
{
    unsigned u = __float_as_uint(f);
    return (u >> 31) ? ~u : (u | 0x80000000u);
}
__device__ inline float unmapf(unsigned u)
{
    return (u >> 31) ? __uint_as_float(u ^ 0x80000000u) : __uint_as_float(~u);
}

// ---------------------------------------------------------------------------
// 8-wave split-bf16 MFMA GEMM (NT): C[M,N] = A[M,K] @ B[N,K]^T as
// hi*hi + hi*lo + lo*hi (fp32 accumulate). 512 thr = 8 waves (4 wy x 2 wx),
// tile 128x128, BK=32, double-buffered 2x32KB LDS via global_load_lds w=16.
// XCD-aware swizzle for L2 locality. K mult of 32; M,N mult of 128.
// LESSONS ENCODED:
//  - round 6: no cross-kernel ticket fusion (threadfence L2 wb/inv >> gap).
//  - round 8: the mask path is an EXACT-BITS contract — rowmax/tmax/thr must
//    be bit-identical to sextract's recompute; "few-ulp guard" tricks
//    compound through the 8-layer recurrence and fail.
// ---------------------------------------------------------------------------
template <int BIAS, int RELU, int WF32, int WSPLIT>
__global__ __launch_bounds__(512, 2) void mgemm8_k(
    const u16* __restrict__ Ahi, const u16* __restrict__ Alo,
    const u16* __restrict__ Bhi, const u16* __restrict__ Blo,
    float* __restrict__ C, u16* __restrict__ Chi, u16* __restrict__ Clo,
    const float* __restrict__ bias,
    int K, int lda, int ldb, int ldc,
    long sAoff, long sBoff, long sCoff)
{
    __shared__ __align__(16) u16 smem[2 * 2048 * 8];   // 64 KB

    const int bz = blockIdx.z;
    Ahi += bz * sAoff;  Alo += bz * sAoff;
    Bhi += bz * sBoff;  Blo += bz * sBoff;
    const long cOff = (long)bz * sCoff;

    // XCD swizzle of the per-z 2D grid (nwg % 8 == 0 at every call site)
    const int gx = gridDim.x, nwg = gx * gridDim.y;
    int lin = blockIdx.y * gx + blockIdx.x;
    lin = (lin & 7) * (nwg >> 3) + (lin >> 3);
    const int bx = lin % gx, by = lin / gx;

    const int tid  = threadIdx.x;
    const int lane = tid & 63;
    const int wave = tid >> 6;
    const int quad = lane >> 4, l15 = lane & 15;
    const int wy = wave >> 1, wx = wave & 1;
    const long mTile = (long)by * 128;
    const long nTile = (long)bx * 128;

    // fragment-read chunk swizzle (row bits 0..3 == l15 for all frag rows)
    const int fsw = (l15 & 3) ^ ((l15 >> 2) & 3);
    const int cA  = (quad ^ fsw) * 8;              // u16 offset of 16B chunk

    const int sr = tid >> 2;                                   // row 0..127
    const int sc = (tid & 3) ^ ((sr & 3) ^ ((sr >> 2) & 3));   // src chunk
    const long aoff = (mTile + sr) * (long)lda + sc * 8;
    const long boff = (nTile + sr) * (long)ldb + sc * 8;

#define STAGE8(bufi, koff)                                                    \
    {                                                                         \
        u16* lb = (u16*)smem + (bufi) * (2048 * 8) + tid * 8;                 \
        __builtin_amdgcn_global_load_lds(                                     \
            (const __attribute__((address_space(1))) void*)(Ahi + aoff + (koff)), \
            (__attribute__((address_space(3))) void*)(lb), 16, 0, 0);         \
        __builtin_amdgcn_global_load_lds(                                     \
            (const __attribute__((address_space(1))) void*)(Alo + aoff + (koff)), \
            (__attribute__((address_space(3))) void*)(lb + 512 * 8), 16, 0, 0); \
        __builtin_amdgcn_global_load_lds(                                     \
            (const __attribute__((address_space(1))) void*)(Bhi + boff + (koff)), \
            (__attribute__((address_space(3))) void*)(lb + 1024 * 8), 16, 0, 0); \
        __builtin_amdgcn_global_load_lds(                                     \
            (const __attribute__((address_space(1))) void*)(Blo + boff + (koff)), \
            (__attribute__((address_space(3))) void*)(lb + 1536 * 8), 16, 0, 0); \
    }

    f32x4 acc[2][4];
#pragma unroll
    for (int i = 0; i < 2; i++)
#pragma unroll
        for (int j = 0; j < 4; j++)
            acc[i][j] = (f32x4){0.f, 0.f, 0.f, 0.f};

    STAGE8(0, 0)
    int buf = 0;
    const int NT = K >> 5;
    for (int t = 0; t < NT; t++) {
        __syncthreads();                 // buf staged (vmcnt drain) + prev reads done
        if (t + 1 < NT) STAGE8(buf ^ 1, (t + 1) << 5)

        const u16* Lb = (const u16*)smem + buf * (2048 * 8);
        bf16x8 ah[2], al[2], bh[4], bl[4];
#pragma unroll
        for (int i = 0; i < 2; i++) {
            const int off = (wy * 32 + i * 16 + l15) * 32 + cA;
            ah[i] = *(const bf16x8*)(Lb + off);
            al[i] = *(const bf16x8*)(Lb + 512 * 8 + off);
        }
#pragma unroll
        for (int j = 0; j < 4; j++) {
            const int off = (wx * 64 + j * 16 + l15) * 32 + cA;
            bh[j] = *(const bf16x8*)(Lb + 1024 * 8 + off);
            bl[j] = *(const bf16x8*)(Lb + 1536 * 8 + off);
        }

#pragma unroll
        for (int i = 0; i < 2; i++)
#pragma unroll
            for (int j = 0; j < 4; j++) {
                acc[i][j] = __builtin_amdgcn_mfma_f32_16x16x32_bf16(
                    ah[i], bh[j], acc[i][j], 0, 0, 0);
                acc[i][j] = __builtin_amdgcn_mfma_f32_16x16x32_bf16(
                    ah[i], bl[j], acc[i][j], 0, 0, 0);
                acc[i][j] = __builtin_amdgcn_mfma_f32_16x16x32_bf16(
                    al[i], bh[j], acc[i][j], 0, 0, 0);
            }
        buf ^= 1;
    }
#undef STAGE8

    const int mBase = (int)mTile + wy * 32;
    const int nBase = (int)nTile + wx * 64;
#pragma unroll
    for (int i = 0; i < 2; i++) {
#pragma unroll
        for (int j = 0; j < 4; j++) {
            const int n = nBase + j * 16 + l15;
            const float bv = BIAS ? bias[n] : 0.0f;
#pragma unroll
            for (int r = 0; r < 4; r++) {
                const int m = mBase + i * 16 + quad * 4 + r;
                float v = acc[i][j][r] + bv;
                if (RELU) v = fmaxf(v, 0.0f);
                const long o = cOff + (long)m * ldc + n;
                if (WF32) C[o] = v;
                if (WSPLIT) {
                    u16 h, l;
                    splitf(v, h, l);
                    Chi[o] = h;
                    Clo[o] = l;
                }
            }
        }
    }
}

// ---------------------------------------------------------------------------
// 4-wave split-bf16 GEMM (kept for KXT, MI=1: tile 32x128). LDS structure +
// XCD swizzle. Optional zero-sweep of the per-layer mask scratch
// (rowmax/rowcnt/colcnt/tmax) folded into the prologue.
// ---------------------------------------------------------------------------
template <int MI, int BIAS, int RELU, int WF32, int WSPLIT>
__global__ __launch_bounds__(256, 2) void mgemm_k(
    const u16* __restrict__ Ahi, const u16* __restrict__ Alo,
    const u16* __restrict__ Bhi, const u16* __restrict__ Blo,
    float* __restrict__ C, u16* __restrict__ Chi, u16* __restrict__ Clo,
    const float* __restrict__ bias,
    int M, int N, int K, int lda, int ldb, int ldc,
    long sAoff, long sBoff, long sCoff,
    unsigned* __restrict__ zbase, int zn)
{
    constexpr int ACH = MI * 128;        // 16B chunks per A stream per BK-tile
    constexpr int TOT = 2 * ACH + 1024;  // chunks per buffer (Ahi|Alo|Bhi|Blo)
    __shared__ __align__(16) u16 smem[2 * TOT * 8];

    const int bz = blockIdx.z;
    Ahi += bz * sAoff;  Alo += bz * sAoff;
    Bhi += bz * sBoff;  Blo += bz * sBoff;
    const long cOff = (long)bz * sCoff;

    const int gx = gridDim.x, nwg = gx * gridDim.y;
    int lin = blockIdx.y * gx + blockIdx.x;
    lin = (lin & 7) * (nwg >> 3) + (lin >> 3);
    const int bxs = lin % gx, bys = lin / gx;

    const int tid  = threadIdx.x;

    // zero-sweep (only KXT passes zbase != null)
    if (zbase) {
        const int gtid = (blockIdx.y * gx + blockIdx.x) * 256 + tid;
        const int gstr = nwg * 256;
        for (int i = gtid; i < zn; i += gstr) zbase[i] = 0u;
    }

    const int wave = tid >> 6, lane = tid & 63;
    const int quad = lane >> 4, l15 = lane & 15;
    const int wy = wave >> 1, wx = wave & 1;
    const long mTile = (long)bys * (MI * 32);
    const long nTile = (long)bxs * 128;
    const int mBase = (int)mTile + wy * (MI * 16);
    const int nBase = (int)nTile + wx * 64;

    const int fsw = (l15 & 3) ^ ((l15 >> 2) & 3);
    const int cA  = (quad ^ fsw) * 8;

#define STAGE(bufi, koff)                                                     \
    {                                                                         \
        _Pragma("unroll")                                                     \
        for (int s = 0; s < TOT / 256; s++) {                                 \
            const int idx = s * 256 + tid;                                    \
            const u16* sp;  long rowb;  int ldx;  int rel;                    \
            if (idx < ACH)                { sp = Ahi; rel = idx;               rowb = 0; ldx = lda; } \
            else if (idx < 2 * ACH)       { sp = Alo; rel = idx - ACH;         rowb = 0; ldx = lda; } \
            else if (idx < 2 * ACH + 512) { sp = Bhi; rel = idx - 2 * ACH;     rowb = 1; ldx = ldb; } \
            else                          { sp = Blo; rel = idx - 2*ACH - 512; rowb = 1; ldx = ldb; } \
            const long rb = rowb ? nTile : mTile;                             \
            const int r = rel >> 2;                                           \
            const int c = (rel & 3) ^ ((r & 3) ^ ((r >> 2) & 3));             \
            const u16* g = sp + (rb + r) * (long)ldx + (koff) + c * 8;        \
            u16* lp = (u16*)smem + (bufi) * (TOT * 8) + idx * 8;              \
            __builtin_amdgcn_global_load_lds(                                 \
                (const __attribute__((address_space(1))) void*)g,             \
                (__attribute__((address_space(3))) void*)lp, 16, 0, 0);       \
        }                                                                     \
    }

    f32x4 acc[MI][4];
#pragma unroll
    for (int i = 0; i < MI; i++)
#pragma unroll
        for (int j = 0; j < 4; j++)
            acc[i][j] = (f32x4){0.f, 0.f, 0.f, 0.f};

    STAGE(0, 0)
    int buf = 0;
    const int NT = K >> 5;
    for (int t = 0; t < NT; t++) {
        __syncthreads();
        if (t + 1 < NT) STAGE(buf ^ 1, (t + 1) << 5)

        const u16* Lb = (const u16*)smem + buf * (TOT * 8);
        bf16x8 ah[MI], al[MI], bh[4], bl[4];
#pragma unroll
        for (int i = 0; i < MI; i++) {
            const int off = (wy * (MI * 16) + i * 16 + l15) * 32 + cA;
            ah[i] = *(const bf16x8*)(Lb + off);
            al[i] = *(const bf16x8*)(Lb + ACH * 8 + off);
        }
#pragma unroll
        for (int j = 0; j < 4; j++) {
            const int off = (wx * 64 + j * 16 + l15) * 32 + cA;
            bh[j] = *(const bf16x8*)(Lb + 2 * ACH * 8 + off);
            bl[j] = *(const bf16x8*)(Lb + 2 * ACH * 8 + 512 * 8 + off);
        }

#pragma unroll
        for (int i = 0; i < MI; i++)
#pragma unroll
            for (int j = 0; j < 4; j++) {
                acc[i][j] = __builtin_amdgcn_mfma_f32_16x16x32_bf16(
                    ah[i], bh[j], acc[i][j], 0, 0, 0);
                acc[i][j] = __builtin_amdgcn_mfma_f32_16x16x32_bf16(
                    ah[i], bl[j], acc[i][j], 0, 0, 0);
                acc[i][j] = __builtin_amdgcn_mfma_f32_16x16x32_bf16(
                    al[i], bh[j], acc[i][j], 0, 0, 0);
            }
        buf ^= 1;
    }
#undef STAGE

#pragma unroll
    for (int i = 0; i < MI; i++) {
#pragma unroll
        for (int j = 0; j < 4; j++) {
            const int n = nBase + j * 16 + l15;
            const float bv = BIAS ? bias[n] : 0.0f;
#pragma unroll
            for (int r = 0; r < 4; r++) {
                const int m = mBase + i * 16 + quad * 4 + r;
                float v = acc[i][j][r] + bv;
                if (RELU) v = fmaxf(v, 0.0f);
                const long o = cOff + (long)m * ldc + n;
                if (WF32) C[o] = v;
                if (WSPLIT) {
                    u16 h, l;
                    splitf(v, h, l);
                    Chi[o] = h;
                    Clo[o] = l;
                }
            }
        }
    }
}

// ---------------------------------------------------------------------------
// Fused mask path, pass A: per-head Gram tile S = G G^T via one-shot LDS
// staging. ALL 256 tiles/head computed (round-8 symmetric-mirror variant
// FAILED: the threshold is an exact-bits contract; ulp-level perturbations
// compound through the 8-layer recurrence). MFMA order (s{i{j{hh,hl,lh}}})
// IDENTICAL to sextract_k -> same bits. Publishes per-tile per-row maxima
// (tmaxU, exact bits) for pass-B early exit.
// ---------------------------------------------------------------------------
__global__ __launch_bounds__(256, 2) void smax_k(
    const u16* __restrict__ Ghi, const u16* __restrict__ Glo,
    unsigned* __restrict__ rowmaxU, unsigned* __restrict__ tmaxU)
{
    __shared__ __align__(16) u16 gs[4096 * 8];   // 64 KB: Ahi|Alo|Bhi|Blo
    const int h = blockIdx.z;
    const int lda = HH * QQ;
    const u16* Gh = Ghi + h * QQ;
    const u16* Gl = Glo + h * QQ;

    const int gx = gridDim.x, nwg = gx * gridDim.y;   // 16, 256
    int lin = blockIdx.y * gx + blockIdx.x;
    lin = (lin & 7) * (nwg >> 3) + (lin >> 3);
    const int bxs = lin % gx, bys = lin / gx;

    const int tid  = threadIdx.x;
    const int wave = tid >> 6, lane = tid & 63;
    const int quad = lane >> 4, l15 = lane & 15;
    const int wy = wave >> 1, wx = wave & 1;
    const int rT = bys * 128, cT = bxs * 128;
    const int rB = rT + wy * 64;

#define SSTG(src, rowbase, dstbase)                                           \
    _Pragma("unroll")                                                         \
    for (int it = 0; it < 4; it++) {                                          \
        const int idx = it * 256 + tid;                                       \
        const int r = idx >> 3;                                               \
        const int c = (idx & 7) ^ (r & 7);                                    \
        __builtin_amdgcn_global_load_lds(                                     \
            (const __attribute__((address_space(1))) void*)(src + (long)((rowbase) + r) * lda + c * 8), \
            (__attribute__((address_space(3))) void*)((u16*)gs + (dstbase) + idx * 8), 16, 0, 0); \
    }
    SSTG(Gh, rT, 0)
    SSTG(Gl, rT, 8192)
    SSTG(Gh, cT, 16384)
    SSTG(Gl, cT, 24576)
#undef SSTG
    __syncthreads();

    bf16x8 ah[2][4], al[2][4], bh[2][4], bl[2][4];
#pragma unroll
    for (int s = 0; s < 2; s++) {
#pragma unroll
        for (int i = 0; i < 4; i++) {
            const int ra = wy * 64 + i * 16 + l15;
            const int ca = ((s * 4 + quad) ^ (ra & 7)) * 8;
            ah[s][i] = *(const bf16x8*)(gs + ra * 64 + ca);
            al[s][i] = *(const bf16x8*)(gs + 8192 + ra * 64 + ca);
            const int rb = wx * 64 + i * 16 + l15;
            const int cb = ((s * 4 + quad) ^ (rb & 7)) * 8;
            bh[s][i] = *(const bf16x8*)(gs + 16384 + rb * 64 + cb);
            bl[s][i] = *(const bf16x8*)(gs + 24576 + rb * 64 + cb);
        }
    }

    f32x4 acc[4][4];
#pragma unroll
    for (int i = 0; i < 4; i++)
#pragma unroll
        for (int j = 0; j < 4; j++)
            acc[i][j] = (f32x4){0.f, 0.f, 0.f, 0.f};

#pragma unroll
    for (int s = 0; s < 2; s++)
#pragma unroll
        for (int i = 0; i < 4; i++)
#pragma unroll
            for (int j = 0; j < 4; j++) {
                acc[i][j] = __builtin_amdgcn_mfma_f32_16x16x32_bf16(ah[s][i], bh[s][j], acc[i][j], 0, 0, 0);
                acc[i][j] = __builtin_amdgcn_mfma_f32_16x16x32_bf16(ah[s][i], bl[s][j], acc[i][j], 0, 0, 0);
                acc[i][j] = __builtin_amdgcn_mfma_f32_16x16x32_bf16(al[s][i], bh[s][j], acc[i][j], 0, 0, 0);
            }

    const unsigned tBase = (unsigned)((((h << 4) + bys) << 4) + bxs) * 128u;
#pragma unroll
    for (int i = 0; i < 4; i++)
#pragma unroll
        for (int r = 0; r < 4; r++) {
            float mx = acc[i][0][r];
#pragma unroll
            for (int j = 1; j < 4; j++) mx = fmaxf(mx, acc[i][j][r]);
#pragma unroll
            for (int off = 1; off < 16; off <<= 1)
                mx = fmaxf(mx, __shfl_xor(mx, off, 64));
            if (l15 == 0) {
                const int lr = wy * 64 + i * 16 + quad * 4 + r;
                const unsigned mv = mapf(mx);
                atomicMax(&rowmaxU[h * NN + rT + lr], mv);
                atomicMax(&tmaxU[tBase + lr], mv);
            }
        }
}

// ---------------------------------------------------------------------------
// Fused mask path, pass B: EARLY-EXIT via tmaxU (exact bit-level test), else
// recompute IDENTICAL S tile, threshold, count, emit. Column counts for the
// CSR build are aggregated in a 128-slot LDS histogram (block's column window
// is cT..cT+127) and flushed with <=128 global atomics per emitting block.
// ---------------------------------------------------------------------------
__global__ __launch_bounds__(256) void sextract_k(
    const u16* __restrict__ Ghi, const u16* __restrict__ Glo,
    const unsigned* __restrict__ rowmaxU, const unsigned* __restrict__ tmaxU,
    int* __restrict__ rowcnt, unsigned* __restrict__ colcnt,
    unsigned int* __restrict__ entries, int* __restrict__ counter)
{
    const int h = blockIdx.z;
    const u16* Ah = Ghi + h * QQ;
    const u16* Al = Glo + h * QQ;
    const int lda = HH * QQ;

    const int gx = gridDim.x, nwg = gx * gridDim.y;
    int lin = blockIdx.y * gx + blockIdx.x;
    lin = (lin & 7) * (nwg >> 3) + (lin >> 3);
    const int bxs = lin % gx, bys = lin / gx;

    const int tid  = threadIdx.x;
    const int wave = tid >> 6, lane = tid & 63;
    const int quad = lane >> 4, l15 = lane & 15;
    const int wy = wave >> 1, wx = wave & 1;
    const int rB = bys * 128 + wy * 64;
    const int cT = bxs * 128;
    const int cB = cT + wx * 64;

    __shared__ float thrS[128];
    __shared__ int chist[128];
    __shared__ unsigned lbuf[LCAP];
    __shared__ int lcnt, gbase, anyf;
    if (tid == 0) { lcnt = 0; anyf = 0; }
    if (tid < 128) {
        chist[tid] = 0;
        float mx = unmapf(rowmaxU[h * NN + bys * 128 + tid]);
        float thr = (fabsf(mx) > 0.5f) ? mx - 0.5f : 3.402823466e38f;
        thrS[tid] = thr;
        float tm = unmapf(tmaxU[(unsigned)((((h << 4) + bys) << 4) + bxs) * 128u + tid]);
        if (tm >= thr) atomicAdd(&anyf, 1);
    }
    __syncthreads();
    if (anyf == 0) return;   // tile provably empty (exact bit-level test)

    bf16x8 ah[2][4], al[2][4], bh[2][4], bl[2][4];
#pragma unroll
    for (int s = 0; s < 2; s++) {
        const int kk = s * 32 + quad * 8;
#pragma unroll
        for (int i = 0; i < 4; i++) {
            long ar = (long)(rB + i * 16 + l15) * lda + kk;
            ah[s][i] = *(const bf16x8*)(Ah + ar);
            al[s][i] = *(const bf16x8*)(Al + ar);
            long br = (long)(cB + i * 16 + l15) * lda + kk;
            bh[s][i] = *(const bf16x8*)(Ah + br);
            bl[s][i] = *(const bf16x8*)(Al + br);
        }
    }

    f32x4 acc[4][4];
#pragma unroll
    for (int i = 0; i < 4; i++)
#pragma unroll
        for (int j = 0; j < 4; j++)
            acc[i][j] = (f32x4){0.f, 0.f, 0.f, 0.f};

#pragma unroll
    for (int s = 0; s < 2; s++)
#pragma unroll
        for (int i = 0; i < 4; i++)
#pragma unroll
            for (int j = 0; j < 4; j++) {
                acc[i][j] = __builtin_amdgcn_mfma_f32_16x16x32_bf16(ah[s][i], bh[s][j], acc[i][j], 0, 0, 0);
                acc[i][j] = __builtin_amdgcn_mfma_f32_16x16x32_bf16(ah[s][i], bl[s][j], acc[i][j], 0, 0, 0);
                acc[i][j] = __builtin_amdgcn_mfma_f32_16x16x32_bf16(al[s][i], bh[s][j], acc[i][j], 0, 0, 0);
            }

#pragma unroll
    for (int i = 0; i < 4; i++) {
#pragma unroll
        for (int r = 0; r < 4; r++) {
            const int lr  = wy * 64 + i * 16 + quad * 4 + r;
            const int row = h * NN + rB + i * 16 + quad * 4 + r;
            const float thr = thrS[lr];

            int c = 0;
#pragma unroll
            for (int j = 0; j < 4; j++) c += (acc[i][j][r] >= thr) ? 1 : 0;
            int cs = c;
#pragma unroll
            for (int off = 1; off < 16; off <<= 1) cs += __shfl_xor(cs, off, 64);
            if (l15 == 0 && cs > 0) atomicAdd(&rowcnt[row], cs);

#pragma unroll
            for (int j = 0; j < 4; j++) {
                if (acc[i][j][r] >= thr) {
                    const unsigned m = (unsigned)(cB + j * 16 + l15);
                    unsigned ent = ((unsigned)row << 11) | m;
                    atomicAdd(&chist[m & 127], 1);
                    int s2 = atomicAdd(&lcnt, 1);
                    if (s2 < LCAP) {
                        lbuf[s2] = ent;
                    } else {
                        unsigned p = (unsigned)atomicAdd(counter, 1);
                        if (p < ENTRY_CAP) entries[p] = ent;
                    }
                }
            }
        }
    }

    __syncthreads();
    // aggregated colcnt flush (<=128 global atomics per emitting block)
    if (tid < 128) {
        int hc = chist[tid];
        if (hc > 0) atomicAdd(&colcnt[cT + tid], (unsigned)hc);
    }
    int n = lcnt;
    if (n > LCAP) n = LCAP;
    if (n > 0) {
        if (tid == 0) gbase = atomicAdd(counter, n);
        __syncthreads();
        for (int i2 = tid; i2 < n; i2 += 256) {
            unsigned p = (unsigned)(gbase + i2);
            if (p < ENTRY_CAP) entries[p] = lbuf[i2];
        }
    }
}

// ---------------------------------------------------------------------------
// Parallel CSR build: scan (1 block: 2048-wide exclusive scan of colcnt ->
// colOff + cursor init) + two-level scatter (per-block LDS histogram ->
// one colCur reservation atomic per distinct column per block -> LDS-cursor
// placement). Kept as a SEPARATE kernel: round-8's fence-free inline scan
// shipped with the failed symmetric-smax change; kernel-boundary ordering
// is the proven-correct synchronization here.
// ---------------------------------------------------------------------------
__global__ __launch_bounds__(256) void scan_k(
    const unsigned* __restrict__ colcnt, int* __restrict__ colOff,
    int* __restrict__ colCur)
{
    __shared__ int part[256];
    const int t = threadIdx.x;
    int e[8];
    int s = 0;
#pragma unroll
    for (int i = 0; i < 8; i++) { e[i] = s; s += (int)colcnt[t * 8 + i]; }
    part[t] = s;
    __syncthreads();
    for (int off = 1; off < 256; off <<= 1) {
        int x = (t >= off) ? part[t - off] : 0;
        __syncthreads();
        part[t] += x;
        __syncthreads();
    }
    int base = (t > 0) ? part[t - 1] : 0;
#pragma unroll
    for (int i = 0; i < 8; i++) {
        colOff[t * 8 + i] = base + e[i];
        colCur[t * 8 + i] = base + e[i];
    }
    if (t == 255) colOff[NN] = part[255];
}

__global__ __launch_bounds__(256) void scatter_k(
    const unsigned int* __restrict__ entries, const int* __restrict__ counter,
    unsigned int* __restrict__ csr, int* __restrict__ colCur)
{
    __shared__ int hist[NN];   // 8 KB: per-chunk histogram, then local cursor
    __shared__ int base[NN];   // 8 KB: reserved global base per column
    int cnt = *counter;
    if (cnt > ENTRY_CAP) cnt = ENTRY_CAP;
    const int nb = gridDim.x;
    const int chunk = (cnt + nb - 1) / nb;
    const int s0 = blockIdx.x * chunk;
    int s1 = s0 + chunk;
    if (s1 > cnt) s1 = cnt;
    if (s0 >= s1) return;

    for (int i = threadIdx.x; i < NN; i += 256) hist[i] = 0;
    __syncthreads();
    for (int i = s0 + threadIdx.x; i < s1; i += 256)
        atomicAdd(&hist[entries[i] & 2047], 1);
    __syncthreads();
    for (int i = threadIdx.x; i < NN; i += 256) {
        int hcount = hist[i];
        base[i] = (hcount > 0) ? atomicAdd(&colCur[i], hcount) : 0;
        hist[i] = 0;   // reuse as local cursor
    }
    __syncthreads();
    for (int i = s0 + threadIdx.x; i < s1; i += 256) {
        unsigned v = entries[i];
        int m = v & 2047;
        int off = atomicAdd(&hist[m], 1);
        csr[base[m] + off] = v;
    }
}

// ---------------------------------------------------------------------------
// split / splitall (x4 work/thread + counters zero; hoisted out of the loop)
// / splitc / apply(inline wrecip) / ff2red(+attnT writeback) / transpose
// ---------------------------------------------------------------------------
__global__ __launch_bounds__(256) void split_k(
    const float* __restrict__ src, u16* __restrict__ hi, u16* __restrict__ lo)
{
    int i = blockIdx.x * 256 + threadIdx.x;
    float4 v = ((const float4*)src)[i];
    ushort4 hv, lv;
    splitf(v.x, hv.x, lv.x);
    splitf(v.y, hv.y, lv.y);
    splitf(v.z, hv.z, lv.z);
    splitf(v.w, hv.w, lv.w);
    ((ushort4*)hi)[i] = hv;
    ((ushort4*)lo)[i] = lv;
}

// initial split that also seeds attnT = X^T
__global__ __launch_bounds__(256) void splitc_k(
    const float* __restrict__ src, u16* __restrict__ hi, u16* __restrict__ lo,
    float* __restrict__ cpy)
{
    int i = blockIdx.x * 256 + threadIdx.x;
    float4 v = ((const float4*)src)[i];
    ((float4*)cpy)[i] = v;
    ushort4 hv, lv;
    splitf(v.x, hv.x, lv.x);
    splitf(v.y, hv.y, lv.y);
    splitf(v.z, hv.z, lv.z);
    splitf(v.w, hv.w, lv.w);
    ((ushort4*)hi)[i] = hv;
    ((ushort4*)lo)[i] = lv;
}

// one-shot split of ALL layers' weights; 4 coalesced sweeps per thread
// (region boundaries are multiples of 1024 float4; bit-identical outputs,
// pure thread remap) + counters zero.
__global__ __launch_bounds__(256) void splitall_k(
    const float* __restrict__ K_, const float* __restrict__ V_,
    const float* __restrict__ W1_, const float* __restrict__ W2_,
    u16* __restrict__ KhiA, u16* __restrict__ KloA,
    u16* __restrict__ VhiA, u16* __restrict__ VloA,
    u16* __restrict__ W1hiA, u16* __restrict__ W1loA,
    u16* __restrict__ W2hiA, u16* __restrict__ W2loA,
    int* __restrict__ counters)
{
    if (blockIdx.x == 0 && threadIdx.x < LL) counters[threadIdx.x] = 0;
    const int li  = blockIdx.x / 800;
    const int sub = blockIdx.x % 800;
#pragma unroll
    for (int jj = 0; jj < 4; jj++) {
        int i = sub * 1024 + jj * 256 + threadIdx.x;  // float4 idx in layer
        const float* s;
        u16 *h, *l;
        int off;
        if (i < 32768) {
            s = K_ + (long)li * 131072;
            h = KhiA + (long)li * 131072;  l = KloA + (long)li * 131072;
            off = i;
        } else if (i < 294912) {
            s = V_ + (long)li * 1048576;
            h = VhiA + (long)li * 1048576; l = VloA + (long)li * 1048576;
            off = i - 32768;
        } else if (i < 557056) {
            s = W1_ + (long)li * 1048576;
            h = W1hiA + (long)li * 1048576; l = W1loA + (long)li * 1048576;
            off = i - 294912;
        } else {
            s = W2_ + (long)li * 1048576;
            h = W2hiA + (long)li * 1048576; l = W2loA + (long)li * 1048576;
            off = i - 557056;
        }
        float4 v = ((const float4*)s)[off];
        ushort4 hv, lv;
        splitf(v.x, hv.x, lv.x);
        splitf(v.y, hv.y, lv.y);
        splitf(v.z, hv.z, lv.z);
        splitf(v.w, hv.w, lv.w);
        ((ushort4*)h)[off] = hv;
        ((ushort4*)l)[off] = lv;
    }
}

__global__ __launch_bounds__(256) void apply_k(
    const unsigned int* __restrict__ csr, const int* __restrict__ colOff,
    const unsigned* __restrict__ rowmaxU, const int* __restrict__ rowcnt,
    const float* __restrict__ Yt, float* __restrict__ attnT)
{
    const int total = colOff[NN];
    const int tid = threadIdx.x;

    for (int base = blockIdx.x * CHUNK; base < total;
         base += gridDim.x * CHUNK) {
        int end = base + CHUNK;
        if (end > total) end = total;

        float a0 = 0.0f, a1 = 0.0f;
        int curM = -1;
        for (int e = base; e < end; e++) {
            unsigned v = csr[e];
            int m = v & 2047;
            int row = (int)(v >> 11);
            if (m != curM) {
                if (curM >= 0) {
                    atomicAdd(&attnT[(long)curM * DD + tid], a0);
                    atomicAdd(&attnT[(long)curM * DD + tid + 256], a1);
                }
                curM = m;
                a0 = a1 = 0.0f;
            }
            float mx = unmapf(rowmaxU[row]);
            float w = (fabsf(mx) > 0.5f)
                          ? 1.0f / fmaxf((float)rowcnt[row], 1.0f) : 0.0f;
            const float* y = Yt + (long)row * DD;
            a0 += w * y[tid];
            a1 += w * y[tid + 256];
        }
        if (curM >= 0) {
            atomicAdd(&attnT[(long)curM * DD + tid], a0);
            atomicAdd(&attnT[(long)curM * DD + tid + 256], a1);
        }
    }
}

__global__ __launch_bounds__(256) void ff2red_k(
    const float* __restrict__ Cpart, const float* __restrict__ b2,
    float* __restrict__ attnT, float* __restrict__ Xn,
    u16* __restrict__ Xhi, u16* __restrict__ Xlo)
{
    int i = blockIdx.x * 256 + threadIdx.x;
    float4 v0 = ((const float4*)(Cpart))[i];
    float4 v1 = ((const float4*)(Cpart + 1048576))[i];
    float4 v2 = ((const float4*)(Cpart + 2097152))[i];
    float4 v3 = ((const float4*)(Cpart + 3145728))[i];
    float4 bv = ((const float4*)b2)[i & 127];
    float4 rv = ((const float4*)attnT)[i];
    float4 o;
    o.x = v0.x + v1.x + v2.x + v3.x + bv.x + rv.x;
    o.y = v0.y + v1.y + v2.y + v3.y + bv.y + rv.y;
    o.z = v0.z + v1.z + v2.z + v3.z + bv.z + rv.z;
    o.w = v0.w + v1.w + v2.w + v3.w + bv.w + rv.w;
    ((float4*)Xn)[i] = o;
    ((float4*)attnT)[i] = o;           // seed next layer's residual base
    ushort4 hv, lv;
    splitf(o.x, hv.x, lv.x);
    splitf(o.y, hv.y, lv.y);
    splitf(o.z, hv.z, lv.z);
    splitf(o.w, hv.w, lv.w);
    ((ushort4*)Xhi)[i] = hv;
    ((ushort4*)Xlo)[i] = lv;
}

__global__ __launch_bounds__(256) void transpose_k(
    const float* __restrict__ src, float* __restrict__ dst, int R, int C)
{
    __shared__ float t[32][33];
    int tx = threadIdx.x & 31, ty = threadIdx.x >> 5;
    int c0 = blockIdx.x * 32, r0 = blockIdx.y * 32;
#pragma unroll
    for (int k = 0; k < 4; k++)
        t[ty + 8 * k][tx] = src[(long)(r0 + ty + 8 * k) * C + c0 + tx];
    __syncthreads();
#pragma unroll
    for (int k = 0; k < 4; k++)
        dst[(long)(c0 + ty + 8 * k) * R + r0 + tx] = t[tx][ty + 8 * k];
}

// ---------------------------------------------------------------------------
// Workspace layout (~193 MB < 256 MiB workspace).
// ---------------------------------------------------------------------------
extern "C" void kernel_launch(void* const* d_in, const int* in_sizes, int n_in,
                              void* d_out, int out_size, void* d_ws, size_t ws_size,
                              hipStream_t stream)
{
    const float* X0 = (const float*)d_in[0];
    const float* Kw = (const float*)d_in[1];
    const float* Vw = (const float*)d_in[2];
    const float* W1 = (const float*)d_in[3];
    const float* b1 = (const float*)d_in[4];
    const float* W2 = (const float*)d_in[5];
    const float* b2 = (const float*)d_in[6];
    float* out = (float*)d_out;

    float* R0    = (float*)d_ws;
    float* Yt    = R0;                       // 4,194,304  [H,NN,DD] fp32
    u16*   ff1hi = (u16*)(R0 + 4194304);
    u16*   ff1lo = (u16*)(R0 + 6291456);
    float* Cpart = R0 + 8388608;             // 4,194,304
    float* attnT = R0 + 12582912;            // 1,048,576

    float* ext = R0 + 13631488;
    u16* KXThi = (u16*)ext;                  // 262,144 words
    u16* KXTlo = (u16*)(ext + 262144);
    float* XbufA = ext + 524288;             // 1,048,576
    float* XbufB = ext + 1572864;            // 1,048,576
    u16* Xhi  = (u16*)(ext + 2621440);       // 524,288 words
    u16* Xlo  = (u16*)(ext + 3145728);
    u16* athi = (u16*)(ext + 3670016);
    u16* atlo = (u16*)(ext + 4194304);       // (ext+4718592 .. ext+8003583 free)
    unsigned int* entries = (unsigned int*)(ext + 8003584);  // 131,072
    unsigned int* csr     = (unsigned int*)(ext + 8134656);  // 131,072
    int* colOff   = (int*)(ext + 8265728);   // 2,112
    int* counters = (int*)(ext + 8267840);   // 64
    // contiguous zero region (ZWORDS = 149,504 u32):
    unsigned* rowmaxU = (unsigned*)(ext + 8267904);  // 8,192
    int* rowcnt   = (int*)(ext + 8276096);           // 8,192
    unsigned* colcnt = (unsigned*)(ext + 8284288);   // 2,048
    unsigned* tmaxU = (unsigned*)(ext + 8286336);    // 131,072
    int* colCur   = (int*)(ext + 8417408);           // 2,048
    // all-layer weight splits (u16), 104.9 MB:
    u16* wbase = (u16*)(ext + 8419456);
    u16* KhiA  = wbase;                         // 8 x 131,072
    u16* KloA  = wbase + 1048576;
    u16* VhiA  = wbase + 2097152;               // 8 x 1,048,576
    u16* VloA  = wbase + 10485760;
    u16* W1hiA = wbase + 18874368;
    u16* W1loA = wbase + 27262976;
    u16* W2hiA = wbase + 35651584;
    u16* W2loA = wbase + 44040192;              // ends at 52,428,800 u16

    // all-layer weight split (hoisted) + counters zero
    splitall_k<<<dim3(LL * 800), 256, 0, stream>>>(
        Kw, Vw, W1, W2, KhiA, KloA, VhiA, VloA, W1hiA, W1loA, W2hiA, W2loA,
        counters);

    // XT0 = X0^T [N, D]; split to bf16 hi/lo and seed attnT = XT0
    transpose_k<<<dim3(NN / 32, DD / 32), 256, 0, stream>>>(X0, XbufA, DD, NN);
    splitc_k<<<dim3(1024), 256, 0, stream>>>(XbufA, Xhi, Xlo, attnT);

    float* Xc = XbufA;
    for (int li = 0; li < LL; li++) {
        float* Xn = (li & 1) ? XbufA : XbufB;
        u16* Khi = KhiA + (long)li * 131072;
        u16* Klo = KloA + (long)li * 131072;
        u16* Vhi = VhiA + (long)li * 1048576;
        u16* Vlo = VloA + (long)li * 1048576;
        u16* W1hi = W1hiA + (long)li * 1048576;
        u16* W1lo = W1loA + (long)li * 1048576;
        u16* W2hi = W2hiA + (long)li * 1048576;
        u16* W2lo = W2loA + (long)li * 1048576;

        // 1) KXT = XT @ Kw^T  [2048, 256], K=512 -> hi/lo. MI=1: 128 blocks.
        //    Prologue zero-sweeps rowmax/rowcnt/colcnt/tmax for this layer.
        mgemm_k<1, 0, 0, 0, 1><<<dim3(2, 64, 1), 256, 0, stream>>>(
            Xhi, Xlo, Khi, Klo, nullptr, KXThi, KXTlo, nullptr,
            NN, HH * QQ, DD, DD, DD, HH * QQ, 0, 0, 0,
            rowmaxU, ZWORDS);

        // 2) fused mask path: no S materialization
        smax_k<<<dim3(16, 16, HH), 256, 0, stream>>>(KXThi, KXTlo, rowmaxU, tmaxU);
        sextract_k<<<dim3(16, 16, HH), 256, 0, stream>>>(
            KXThi, KXTlo, rowmaxU, tmaxU, rowcnt, colcnt, entries, counters + li);
        scan_k<<<dim3(1), 256, 0, stream>>>(colcnt, colOff, colCur);
        scatter_k<<<dim3(64), 256, 0, stream>>>(entries, counters + li, csr, colCur);

        // 4) Yt_h = XT @ V_h^T  [NN, DD] fp32, batch H. 8-wave: 64 blk/head.
        mgemm8_k<0, 0, 1, 0><<<dim3(4, 16, HH), 512, 0, stream>>>(
            Xhi, Xlo, Vhi, Vlo, Yt, nullptr, nullptr, nullptr,
            DD, DD, DD, DD, 0, (long)DD * DD, (long)NN * DD);

        // 5) attnT (= XT residual) += sparse combine; split for FF1 input
        apply_k<<<dim3(APPLY_BLOCKS), 256, 0, stream>>>(
            csr, colOff, rowmaxU, rowcnt, Yt, attnT);
        split_k<<<dim3(1024), 256, 0, stream>>>(attnT, athi, atlo);

        // 6) ff1 = relu(attnT @ W1^T + b1)  [NN, DFF] -> hi/lo. 256 blocks.
        mgemm8_k<1, 1, 0, 1><<<dim3(16, 16, 1), 512, 0, stream>>>(
            athi, atlo, W1hi, W1lo, nullptr, ff1hi, ff1lo,
            b1 + (long)li * DFFC,
            DD, DD, DD, DFFC, 0, 0, 0);

        // 7) FF2 split-K=4: 64 blocks x 4.
        mgemm8_k<0, 0, 1, 0><<<dim3(4, 16, 4), 512, 0, stream>>>(
            ff1hi, ff1lo, W2hi, W2lo, Cpart, nullptr, nullptr, nullptr,
            512, DFFC, DFFC, DD, 512, 512, (long)NN * DD);
        ff2red_k<<<dim3(1024), 256, 0, stream>>>(
            Cpart, b2 + (long)li * DD, attnT, Xn, Xhi, Xlo);

        Xc = Xn;
    }

    // out = XT_final^T  [D, N]
    transpose_k<<<dim3(DD / 32, NN / 32), 256, 0, stream>>>(Xc, out, NN, DD);
}

// Round 10
// 1213.082 us; speedup vs baseline: 1.8356x; 1.0107x over previous
//
#include <hip/hip_runtime.h>

// Problem constants
#define LL   8
#define HH   4
#define QQ   64
#define DD   512
#define NN   2048
#define DFFC 2048
#define ENTRY_CAP (1 << 17)
#define CHUNK 8
#define APPLY_BLOCKS 2048
#define LCAP 2048   // per-block LDS entry staging capacity
#define ZWORDS 151552  // rowmaxU(8192)+rowcnt(8192)+colcnt(2048)+tmaxU(131072)+colCur(2048)

typedef short     bf16x8 __attribute__((ext_vector_type(8)));  // 8 bf16 = 4 VGPR
typedef float     f32x4  __attribute__((ext_vector_type(4)));  // MFMA C/D frag
typedef unsigned short u16;

// fp32 -> (hi, lo) bf16 split, RNE. x ~= hi + lo with ~16-bit mantissa coverage.
__device__ inline void splitf(float v, u16& h, u16& l)
{
    unsigned u  = __float_as_uint(v);
    unsigned uh = u + (0x7FFFu + ((u >> 16) & 1u));
    h = (u16)(uh >> 16);
    float fh = __uint_as_float(((unsigned)h) << 16);
    float r  = v - fh;
    unsigned ur = __float_as_uint(r);
    unsigned ul = ur + (0x7FFFu + ((ur >> 16) & 1u));
    l = (u16)(ul >> 16);
}

// Monotone fp32 <-> uint mapping for atomicMax on floats (no NaNs in data).
__device__ inline unsigned mapf(float f)
{
    unsigned u = __float_as_uint(f);
    return (u >> 31) ? ~u : (u | 0x80000000u);
}
__device__ inline float unmapf(unsigned u)
{
    return (u >> 31) ? __uint_as_float(u ^ 0x80000000u) : __uint_as_float(~u);
}

// ---------------------------------------------------------------------------
// 8-wave split-bf16 MFMA GEMM (NT): C[M,N] = A[M,K] @ B[N,K]^T as
// hi*hi + hi*lo + lo*hi (fp32 accumulate). 512 thr = 8 waves (4 wy x 2 wx),
// tile 128x128, BK=32, double-buffered 2x32KB LDS via global_load_lds w=16.
// XCD-aware swizzle for L2 locality. K mult of 32; M,N mult of 128.
// LESSONS ENCODED:
//  - round 6: no cross-kernel ticket fusion (threadfence L2 wb/inv >> gap).
//  - round 8: the mask path is an EXACT-BITS contract — rowmax/tmax/thr must
//    be bit-identical to sextract's recompute; ulp-level tricks compound
//    through the 8-layer recurrence and fail.
// ---------------------------------------------------------------------------
template <int BIAS, int RELU, int WF32, int WSPLIT>
__global__ __launch_bounds__(512, 2) void mgemm8_k(
    const u16* __restrict__ Ahi, const u16* __restrict__ Alo,
    const u16* __restrict__ Bhi, const u16* __restrict__ Blo,
    float* __restrict__ C, u16* __restrict__ Chi, u16* __restrict__ Clo,
    const float* __restrict__ bias,
    int K, int lda, int ldb, int ldc,
    long sAoff, long sBoff, long sCoff)
{
    __shared__ __align__(16) u16 smem[2 * 2048 * 8];   // 64 KB

    const int bz = blockIdx.z;
    Ahi += bz * sAoff;  Alo += bz * sAoff;
    Bhi += bz * sBoff;  Blo += bz * sBoff;
    const long cOff = (long)bz * sCoff;

    // XCD swizzle of the per-z 2D grid (nwg % 8 == 0 at every call site)
    const int gx = gridDim.x, nwg = gx * gridDim.y;
    int lin = blockIdx.y * gx + blockIdx.x;
    lin = (lin & 7) * (nwg >> 3) + (lin >> 3);
    const int bx = lin % gx, by = lin / gx;

    const int tid  = threadIdx.x;
    const int lane = tid & 63;
    const int wave = tid >> 6;
    const int quad = lane >> 4, l15 = lane & 15;
    const int wy = wave >> 1, wx = wave & 1;
    const long mTile = (long)by * 128;
    const long nTile = (long)bx * 128;

    // fragment-read chunk swizzle (row bits 0..3 == l15 for all frag rows)
    const int fsw = (l15 & 3) ^ ((l15 >> 2) & 3);
    const int cA  = (quad ^ fsw) * 8;              // u16 offset of 16B chunk

    const int sr = tid >> 2;                                   // row 0..127
    const int sc = (tid & 3) ^ ((sr & 3) ^ ((sr >> 2) & 3));   // src chunk
    const long aoff = (mTile + sr) * (long)lda + sc * 8;
    const long boff = (nTile + sr) * (long)ldb + sc * 8;

#define STAGE8(bufi, koff)                                                    \
    {                                                                         \
        u16* lb = (u16*)smem + (bufi) * (2048 * 8) + tid * 8;                 \
        __builtin_amdgcn_global_load_lds(                                     \
            (const __attribute__((address_space(1))) void*)(Ahi + aoff + (koff)), \
            (__attribute__((address_space(3))) void*)(lb), 16, 0, 0);         \
        __builtin_amdgcn_global_load_lds(                                     \
            (const __attribute__((address_space(1))) void*)(Alo + aoff + (koff)), \
            (__attribute__((address_space(3))) void*)(lb + 512 * 8), 16, 0, 0); \
        __builtin_amdgcn_global_load_lds(                                     \
            (const __attribute__((address_space(1))) void*)(Bhi + boff + (koff)), \
            (__attribute__((address_space(3))) void*)(lb + 1024 * 8), 16, 0, 0); \
        __builtin_amdgcn_global_load_lds(                                     \
            (const __attribute__((address_space(1))) void*)(Blo + boff + (koff)), \
            (__attribute__((address_space(3))) void*)(lb + 1536 * 8), 16, 0, 0); \
    }

    f32x4 acc[2][4];
#pragma unroll
    for (int i = 0; i < 2; i++)
#pragma unroll
        for (int j = 0; j < 4; j++)
            acc[i][j] = (f32x4){0.f, 0.f, 0.f, 0.f};

    STAGE8(0, 0)
    int buf = 0;
    const int NT = K >> 5;
    for (int t = 0; t < NT; t++) {
        __syncthreads();                 // buf staged (vmcnt drain) + prev reads done
        if (t + 1 < NT) STAGE8(buf ^ 1, (t + 1) << 5)

        const u16* Lb = (const u16*)smem + buf * (2048 * 8);
        bf16x8 ah[2], al[2], bh[4], bl[4];
#pragma unroll
        for (int i = 0; i < 2; i++) {
            const int off = (wy * 32 + i * 16 + l15) * 32 + cA;
            ah[i] = *(const bf16x8*)(Lb + off);
            al[i] = *(const bf16x8*)(Lb + 512 * 8 + off);
        }
#pragma unroll
        for (int j = 0; j < 4; j++) {
            const int off = (wx * 64 + j * 16 + l15) * 32 + cA;
            bh[j] = *(const bf16x8*)(Lb + 1024 * 8 + off);
            bl[j] = *(const bf16x8*)(Lb + 1536 * 8 + off);
        }

#pragma unroll
        for (int i = 0; i < 2; i++)
#pragma unroll
            for (int j = 0; j < 4; j++) {
                acc[i][j] = __builtin_amdgcn_mfma_f32_16x16x32_bf16(
                    ah[i], bh[j], acc[i][j], 0, 0, 0);
                acc[i][j] = __builtin_amdgcn_mfma_f32_16x16x32_bf16(
                    ah[i], bl[j], acc[i][j], 0, 0, 0);
                acc[i][j] = __builtin_amdgcn_mfma_f32_16x16x32_bf16(
                    al[i], bh[j], acc[i][j], 0, 0, 0);
            }
        buf ^= 1;
    }
#undef STAGE8

    const int mBase = (int)mTile + wy * 32;
    const int nBase = (int)nTile + wx * 64;
#pragma unroll
    for (int i = 0; i < 2; i++) {
#pragma unroll
        for (int j = 0; j < 4; j++) {
            const int n = nBase + j * 16 + l15;
            const float bv = BIAS ? bias[n] : 0.0f;
#pragma unroll
            for (int r = 0; r < 4; r++) {
                const int m = mBase + i * 16 + quad * 4 + r;
                float v = acc[i][j][r] + bv;
                if (RELU) v = fmaxf(v, 0.0f);
                const long o = cOff + (long)m * ldc + n;
                if (WF32) C[o] = v;
                if (WSPLIT) {
                    u16 h, l;
                    splitf(v, h, l);
                    Chi[o] = h;
                    Clo[o] = l;
                }
            }
        }
    }
}

// ---------------------------------------------------------------------------
// 4-wave split-bf16 GEMM (kept for KXT, MI=1: tile 32x128). LDS structure +
// XCD swizzle. Optional zero-sweep of the per-layer mask scratch
// (rowmax/rowcnt/colcnt/tmax/colCur) folded into the prologue.
// ---------------------------------------------------------------------------
template <int MI, int BIAS, int RELU, int WF32, int WSPLIT>
__global__ __launch_bounds__(256, 2) void mgemm_k(
    const u16* __restrict__ Ahi, const u16* __restrict__ Alo,
    const u16* __restrict__ Bhi, const u16* __restrict__ Blo,
    float* __restrict__ C, u16* __restrict__ Chi, u16* __restrict__ Clo,
    const float* __restrict__ bias,
    int M, int N, int K, int lda, int ldb, int ldc,
    long sAoff, long sBoff, long sCoff,
    unsigned* __restrict__ zbase, int zn)
{
    constexpr int ACH = MI * 128;        // 16B chunks per A stream per BK-tile
    constexpr int TOT = 2 * ACH + 1024;  // chunks per buffer (Ahi|Alo|Bhi|Blo)
    __shared__ __align__(16) u16 smem[2 * TOT * 8];

    const int bz = blockIdx.z;
    Ahi += bz * sAoff;  Alo += bz * sAoff;
    Bhi += bz * sBoff;  Blo += bz * sBoff;
    const long cOff = (long)bz * sCoff;

    const int gx = gridDim.x, nwg = gx * gridDim.y;
    int lin = blockIdx.y * gx + blockIdx.x;
    lin = (lin & 7) * (nwg >> 3) + (lin >> 3);
    const int bxs = lin % gx, bys = lin / gx;

    const int tid  = threadIdx.x;

    // zero-sweep (only KXT passes zbase != null)
    if (zbase) {
        const int gtid = (blockIdx.y * gx + blockIdx.x) * 256 + tid;
        const int gstr = nwg * 256;
        for (int i = gtid; i < zn; i += gstr) zbase[i] = 0u;
    }

    const int wave = tid >> 6, lane = tid & 63;
    const int quad = lane >> 4, l15 = lane & 15;
    const int wy = wave >> 1, wx = wave & 1;
    const long mTile = (long)bys * (MI * 32);
    const long nTile = (long)bxs * 128;
    const int mBase = (int)mTile + wy * (MI * 16);
    const int nBase = (int)nTile + wx * 64;

    const int fsw = (l15 & 3) ^ ((l15 >> 2) & 3);
    const int cA  = (quad ^ fsw) * 8;

#define STAGE(bufi, koff)                                                     \
    {                                                                         \
        _Pragma("unroll")                                                     \
        for (int s = 0; s < TOT / 256; s++) {                                 \
            const int idx = s * 256 + tid;                                    \
            const u16* sp;  long rowb;  int ldx;  int rel;                    \
            if (idx < ACH)                { sp = Ahi; rel = idx;               rowb = 0; ldx = lda; } \
            else if (idx < 2 * ACH)       { sp = Alo; rel = idx - ACH;         rowb = 0; ldx = lda; } \
            else if (idx < 2 * ACH + 512) { sp = Bhi; rel = idx - 2 * ACH;     rowb = 1; ldx = ldb; } \
            else                          { sp = Blo; rel = idx - 2*ACH - 512; rowb = 1; ldx = ldb; } \
            const long rb = rowb ? nTile : mTile;                             \
            const int r = rel >> 2;                                           \
            const int c = (rel & 3) ^ ((r & 3) ^ ((r >> 2) & 3));             \
            const u16* g = sp + (rb + r) * (long)ldx + (koff) + c * 8;        \
            u16* lp = (u16*)smem + (bufi) * (TOT * 8) + idx * 8;              \
            __builtin_amdgcn_global_load_lds(                                 \
                (const __attribute__((address_space(1))) void*)g,             \
                (__attribute__((address_space(3))) void*)lp, 16, 0, 0);       \
        }                                                                     \
    }

    f32x4 acc[MI][4];
#pragma unroll
    for (int i = 0; i < MI; i++)
#pragma unroll
        for (int j = 0; j < 4; j++)
            acc[i][j] = (f32x4){0.f, 0.f, 0.f, 0.f};

    STAGE(0, 0)
    int buf = 0;
    const int NT = K >> 5;
    for (int t = 0; t < NT; t++) {
        __syncthreads();
        if (t + 1 < NT) STAGE(buf ^ 1, (t + 1) << 5)

        const u16* Lb = (const u16*)smem + buf * (TOT * 8);
        bf16x8 ah[MI], al[MI], bh[4], bl[4];
#pragma unroll
        for (int i = 0; i < MI; i++) {
            const int off = (wy * (MI * 16) + i * 16 + l15) * 32 + cA;
            ah[i] = *(const bf16x8*)(Lb + off);
            al[i] = *(const bf16x8*)(Lb + ACH * 8 + off);
        }
#pragma unroll
        for (int j = 0; j < 4; j++) {
            const int off = (wx * 64 + j * 16 + l15) * 32 + cA;
            bh[j] = *(const bf16x8*)(Lb + 2 * ACH * 8 + off);
            bl[j] = *(const bf16x8*)(Lb + 2 * ACH * 8 + 512 * 8 + off);
        }

#pragma unroll
        for (int i = 0; i < MI; i++)
#pragma unroll
            for (int j = 0; j < 4; j++) {
                acc[i][j] = __builtin_amdgcn_mfma_f32_16x16x32_bf16(
                    ah[i], bh[j], acc[i][j], 0, 0, 0);
                acc[i][j] = __builtin_amdgcn_mfma_f32_16x16x32_bf16(
                    ah[i], bl[j], acc[i][j], 0, 0, 0);
                acc[i][j] = __builtin_amdgcn_mfma_f32_16x16x32_bf16(
                    al[i], bh[j], acc[i][j], 0, 0, 0);
            }
        buf ^= 1;
    }
#undef STAGE

#pragma unroll
    for (int i = 0; i < MI; i++) {
#pragma unroll
        for (int j = 0; j < 4; j++) {
            const int n = nBase + j * 16 + l15;
            const float bv = BIAS ? bias[n] : 0.0f;
#pragma unroll
            for (int r = 0; r < 4; r++) {
                const int m = mBase + i * 16 + quad * 4 + r;
                float v = acc[i][j][r] + bv;
                if (RELU) v = fmaxf(v, 0.0f);
                const long o = cOff + (long)m * ldc + n;
                if (WF32) C[o] = v;
                if (WSPLIT) {
                    u16 h, l;
                    splitf(v, h, l);
                    Chi[o] = h;
                    Clo[o] = l;
                }
            }
        }
    }
}

// ---------------------------------------------------------------------------
// Fused mask path, pass A: per-head Gram tile S = G G^T via one-shot LDS
// staging. ALL 256 tiles/head computed (exact-bits contract). MFMA order
// (s{i{j{hh,hl,lh}}}) IDENTICAL to sextract_k -> same bits. Publishes
// per-tile per-row maxima (tmaxU, exact bits) for pass-B early exit.
// ---------------------------------------------------------------------------
__global__ __launch_bounds__(256, 2) void smax_k(
    const u16* __restrict__ Ghi, const u16* __restrict__ Glo,
    unsigned* __restrict__ rowmaxU, unsigned* __restrict__ tmaxU)
{
    __shared__ __align__(16) u16 gs[4096 * 8];   // 64 KB: Ahi|Alo|Bhi|Blo
    const int h = blockIdx.z;
    const int lda = HH * QQ;
    const u16* Gh = Ghi + h * QQ;
    const u16* Gl = Glo + h * QQ;

    const int gx = gridDim.x, nwg = gx * gridDim.y;   // 16, 256
    int lin = blockIdx.y * gx + blockIdx.x;
    lin = (lin & 7) * (nwg >> 3) + (lin >> 3);
    const int bxs = lin % gx, bys = lin / gx;

    const int tid  = threadIdx.x;
    const int wave = tid >> 6, lane = tid & 63;
    const int quad = lane >> 4, l15 = lane & 15;
    const int wy = wave >> 1, wx = wave & 1;
    const int rT = bys * 128, cT = bxs * 128;
    const int rB = rT + wy * 64;

#define SSTG(src, rowbase, dstbase)                                           \
    _Pragma("unroll")                                                         \
    for (int it = 0; it < 4; it++) {                                          \
        const int idx = it * 256 + tid;                                       \
        const int r = idx >> 3;                                               \
        const int c = (idx & 7) ^ (r & 7);                                    \
        __builtin_amdgcn_global_load_lds(                                     \
            (const __attribute__((address_space(1))) void*)(src + (long)((rowbase) + r) * lda + c * 8), \
            (__attribute__((address_space(3))) void*)((u16*)gs + (dstbase) + idx * 8), 16, 0, 0); \
    }
    SSTG(Gh, rT, 0)
    SSTG(Gl, rT, 8192)
    SSTG(Gh, cT, 16384)
    SSTG(Gl, cT, 24576)
#undef SSTG
    __syncthreads();

    bf16x8 ah[2][4], al[2][4], bh[2][4], bl[2][4];
#pragma unroll
    for (int s = 0; s < 2; s++) {
#pragma unroll
        for (int i = 0; i < 4; i++) {
            const int ra = wy * 64 + i * 16 + l15;
            const int ca = ((s * 4 + quad) ^ (ra & 7)) * 8;
            ah[s][i] = *(const bf16x8*)(gs + ra * 64 + ca);
            al[s][i] = *(const bf16x8*)(gs + 8192 + ra * 64 + ca);
            const int rb = wx * 64 + i * 16 + l15;
            const int cb = ((s * 4 + quad) ^ (rb & 7)) * 8;
            bh[s][i] = *(const bf16x8*)(gs + 16384 + rb * 64 + cb);
            bl[s][i] = *(const bf16x8*)(gs + 24576 + rb * 64 + cb);
        }
    }

    f32x4 acc[4][4];
#pragma unroll
    for (int i = 0; i < 4; i++)
#pragma unroll
        for (int j = 0; j < 4; j++)
            acc[i][j] = (f32x4){0.f, 0.f, 0.f, 0.f};

#pragma unroll
    for (int s = 0; s < 2; s++)
#pragma unroll
        for (int i = 0; i < 4; i++)
#pragma unroll
            for (int j = 0; j < 4; j++) {
                acc[i][j] = __builtin_amdgcn_mfma_f32_16x16x32_bf16(ah[s][i], bh[s][j], acc[i][j], 0, 0, 0);
                acc[i][j] = __builtin_amdgcn_mfma_f32_16x16x32_bf16(ah[s][i], bl[s][j], acc[i][j], 0, 0, 0);
                acc[i][j] = __builtin_amdgcn_mfma_f32_16x16x32_bf16(al[s][i], bh[s][j], acc[i][j], 0, 0, 0);
            }

    const unsigned tBase = (unsigned)((((h << 4) + bys) << 4) + bxs) * 128u;
#pragma unroll
    for (int i = 0; i < 4; i++)
#pragma unroll
        for (int r = 0; r < 4; r++) {
            float mx = acc[i][0][r];
#pragma unroll
            for (int j = 1; j < 4; j++) mx = fmaxf(mx, acc[i][j][r]);
#pragma unroll
            for (int off = 1; off < 16; off <<= 1)
                mx = fmaxf(mx, __shfl_xor(mx, off, 64));
            if (l15 == 0) {
                const int lr = wy * 64 + i * 16 + quad * 4 + r;
                const unsigned mv = mapf(mx);
                atomicMax(&rowmaxU[h * NN + rT + lr], mv);
                atomicMax(&tmaxU[tBase + lr], mv);
            }
        }
}

// ---------------------------------------------------------------------------
// Fused mask path, pass B: EARLY-EXIT via tmaxU (exact bit-level test), else
// recompute IDENTICAL S tile, threshold, count, emit. Column counts for the
// CSR build are aggregated in a 128-slot LDS histogram (block's column window
// is cT..cT+127) and flushed with <=128 global atomics per emitting block.
// ---------------------------------------------------------------------------
__global__ __launch_bounds__(256) void sextract_k(
    const u16* __restrict__ Ghi, const u16* __restrict__ Glo,
    const unsigned* __restrict__ rowmaxU, const unsigned* __restrict__ tmaxU,
    int* __restrict__ rowcnt, unsigned* __restrict__ colcnt,
    unsigned int* __restrict__ entries, int* __restrict__ counter)
{
    const int h = blockIdx.z;
    const u16* Ah = Ghi + h * QQ;
    const u16* Al = Glo + h * QQ;
    const int lda = HH * QQ;

    const int gx = gridDim.x, nwg = gx * gridDim.y;
    int lin = blockIdx.y * gx + blockIdx.x;
    lin = (lin & 7) * (nwg >> 3) + (lin >> 3);
    const int bxs = lin % gx, bys = lin / gx;

    const int tid  = threadIdx.x;
    const int wave = tid >> 6, lane = tid & 63;
    const int quad = lane >> 4, l15 = lane & 15;
    const int wy = wave >> 1, wx = wave & 1;
    const int rB = bys * 128 + wy * 64;
    const int cT = bxs * 128;
    const int cB = cT + wx * 64;

    __shared__ float thrS[128];
    __shared__ int chist[128];
    __shared__ unsigned lbuf[LCAP];
    __shared__ int lcnt, gbase, anyf;
    if (tid == 0) { lcnt = 0; anyf = 0; }
    if (tid < 128) {
        chist[tid] = 0;
        float mx = unmapf(rowmaxU[h * NN + bys * 128 + tid]);
        float thr = (fabsf(mx) > 0.5f) ? mx - 0.5f : 3.402823466e38f;
        thrS[tid] = thr;
        float tm = unmapf(tmaxU[(unsigned)((((h << 4) + bys) << 4) + bxs) * 128u + tid]);
        if (tm >= thr) atomicAdd(&anyf, 1);
    }
    __syncthreads();
    if (anyf == 0) return;   // tile provably empty (exact bit-level test)

    bf16x8 ah[2][4], al[2][4], bh[2][4], bl[2][4];
#pragma unroll
    for (int s = 0; s < 2; s++) {
        const int kk = s * 32 + quad * 8;
#pragma unroll
        for (int i = 0; i < 4; i++) {
            long ar = (long)(rB + i * 16 + l15) * lda + kk;
            ah[s][i] = *(const bf16x8*)(Ah + ar);
            al[s][i] = *(const bf16x8*)(Al + ar);
            long br = (long)(cB + i * 16 + l15) * lda + kk;
            bh[s][i] = *(const bf16x8*)(Ah + br);
            bl[s][i] = *(const bf16x8*)(Al + br);
        }
    }

    f32x4 acc[4][4];
#pragma unroll
    for (int i = 0; i < 4; i++)
#pragma unroll
        for (int j = 0; j < 4; j++)
            acc[i][j] = (f32x4){0.f, 0.f, 0.f, 0.f};

#pragma unroll
    for (int s = 0; s < 2; s++)
#pragma unroll
        for (int i = 0; i < 4; i++)
#pragma unroll
            for (int j = 0; j < 4; j++) {
                acc[i][j] = __builtin_amdgcn_mfma_f32_16x16x32_bf16(ah[s][i], bh[s][j], acc[i][j], 0, 0, 0);
                acc[i][j] = __builtin_amdgcn_mfma_f32_16x16x32_bf16(ah[s][i], bl[s][j], acc[i][j], 0, 0, 0);
                acc[i][j] = __builtin_amdgcn_mfma_f32_16x16x32_bf16(al[s][i], bh[s][j], acc[i][j], 0, 0, 0);
            }

#pragma unroll
    for (int i = 0; i < 4; i++) {
#pragma unroll
        for (int r = 0; r < 4; r++) {
            const int lr  = wy * 64 + i * 16 + quad * 4 + r;
            const int row = h * NN + rB + i * 16 + quad * 4 + r;
            const float thr = thrS[lr];

            int c = 0;
#pragma unroll
            for (int j = 0; j < 4; j++) c += (acc[i][j][r] >= thr) ? 1 : 0;
            int cs = c;
#pragma unroll
            for (int off = 1; off < 16; off <<= 1) cs += __shfl_xor(cs, off, 64);
            if (l15 == 0 && cs > 0) atomicAdd(&rowcnt[row], cs);

#pragma unroll
            for (int j = 0; j < 4; j++) {
                if (acc[i][j][r] >= thr) {
                    const unsigned m = (unsigned)(cB + j * 16 + l15);
                    unsigned ent = ((unsigned)row << 11) | m;
                    atomicAdd(&chist[m & 127], 1);
                    int s2 = atomicAdd(&lcnt, 1);
                    if (s2 < LCAP) {
                        lbuf[s2] = ent;
                    } else {
                        unsigned p = (unsigned)atomicAdd(counter, 1);
                        if (p < ENTRY_CAP) entries[p] = ent;
                    }
                }
            }
        }
    }

    __syncthreads();
    // aggregated colcnt flush (<=128 global atomics per emitting block)
    if (tid < 128) {
        int hc = chist[tid];
        if (hc > 0) atomicAdd(&colcnt[cT + tid], (unsigned)hc);
    }
    int n = lcnt;
    if (n > LCAP) n = LCAP;
    if (n > 0) {
        if (tid == 0) gbase = atomicAdd(counter, n);
        __syncthreads();
        for (int i2 = tid; i2 < n; i2 += 256) {
            unsigned p = (unsigned)(gbase + i2);
            if (p < ENTRY_CAP) entries[p] = lbuf[i2];
        }
    }
}

// ---------------------------------------------------------------------------
// CSR build in ONE kernel: every block independently computes the 2048-wide
// exclusive scan of colcnt in LDS (deterministic -> identical across blocks;
// colcnt complete at the kernel boundary — no cross-block communication).
// Block 0 publishes colOff for apply_k. Placement: per-block LDS histogram ->
// one zero-based colCur reservation atomic per distinct column per block ->
// LDS-cursor placement at offL[m] + reservation. Replaces scan_k + scatter_k
// (one less launch per layer); within-column order is a permutation, which
// only perturbs apply_k's (already atomic-nondeterministic) float sum order.
// ---------------------------------------------------------------------------
__global__ __launch_bounds__(256) void scatter_k(
    const unsigned int* __restrict__ entries, const int* __restrict__ counter,
    const unsigned* __restrict__ colcnt,
    unsigned int* __restrict__ csr, int* __restrict__ colOff,
    int* __restrict__ colCur)
{
    __shared__ int offL[NN + 8];   // local colOff scan (identical per block)
    __shared__ int part[256];
    __shared__ int hist[NN];       // per-chunk histogram, then local cursor
    __shared__ int base[NN];       // reserved global base per column
    const int t = threadIdx.x;

    // block-local exclusive scan of colcnt
    int e[8];
    int s = 0;
#pragma unroll
    for (int i = 0; i < 8; i++) { e[i] = s; s += (int)colcnt[t * 8 + i]; }
    part[t] = s;
    __syncthreads();
    for (int off = 1; off < 256; off <<= 1) {
        int x = (t >= off) ? part[t - off] : 0;
        __syncthreads();
        part[t] += x;
        __syncthreads();
    }
    int b0 = (t > 0) ? part[t - 1] : 0;
#pragma unroll
    for (int i = 0; i < 8; i++) offL[t * 8 + i] = b0 + e[i];
    if (t == 255) offL[NN] = part[255];
    __syncthreads();

    // block 0 publishes colOff for apply_k (kernel boundary orders it)
    if (blockIdx.x == 0)
        for (int i = t; i <= NN; i += 256) colOff[i] = offL[i];

    int cnt = *counter;
    if (cnt > ENTRY_CAP) cnt = ENTRY_CAP;
    const int nb = gridDim.x;
    const int chunk = (cnt + nb - 1) / nb;
    const int s0 = blockIdx.x * chunk;
    int s1 = s0 + chunk;
    if (s1 > cnt) s1 = cnt;
    if (s0 >= s1) return;

    for (int i = t; i < NN; i += 256) hist[i] = 0;
    __syncthreads();
    for (int i = s0 + t; i < s1; i += 256)
        atomicAdd(&hist[entries[i] & 2047], 1);
    __syncthreads();
    for (int i = t; i < NN; i += 256) {
        int hc = hist[i];
        base[i] = (hc > 0) ? (offL[i] + atomicAdd(&colCur[i], hc)) : 0;
        hist[i] = 0;   // reuse as local cursor
    }
    __syncthreads();
    for (int i = s0 + t; i < s1; i += 256) {
        unsigned v = entries[i];
        int m = v & 2047;
        int off = atomicAdd(&hist[m], 1);
        csr[base[m] + off] = v;
    }
}

// ---------------------------------------------------------------------------
// split / splitall (x2 work/thread + counters zero; hoisted out of the loop;
// x4 variant measured SLOWER in round 9 — reverted) / splitc / apply /
// ff2red(+attnT writeback) / transpose
// ---------------------------------------------------------------------------
__global__ __launch_bounds__(256) void split_k(
    const float* __restrict__ src, u16* __restrict__ hi, u16* __restrict__ lo)
{
    int i = blockIdx.x * 256 + threadIdx.x;
    float4 v = ((const float4*)src)[i];
    ushort4 hv, lv;
    splitf(v.x, hv.x, lv.x);
    splitf(v.y, hv.y, lv.y);
    splitf(v.z, hv.z, lv.z);
    splitf(v.w, hv.w, lv.w);
    ((ushort4*)hi)[i] = hv;
    ((ushort4*)lo)[i] = lv;
}

// initial split that also seeds attnT = X^T
__global__ __launch_bounds__(256) void splitc_k(
    const float* __restrict__ src, u16* __restrict__ hi, u16* __restrict__ lo,
    float* __restrict__ cpy)
{
    int i = blockIdx.x * 256 + threadIdx.x;
    float4 v = ((const float4*)src)[i];
    ((float4*)cpy)[i] = v;
    ushort4 hv, lv;
    splitf(v.x, hv.x, lv.x);
    splitf(v.y, hv.y, lv.y);
    splitf(v.z, hv.z, lv.z);
    splitf(v.w, hv.w, lv.w);
    ((ushort4*)hi)[i] = hv;
    ((ushort4*)lo)[i] = lv;
}

// one-shot split of ALL layers' weights; 2 coalesced sweeps per thread
// (region boundaries are multiples of 512 float4) + counters zero.
__global__ __launch_bounds__(256) void splitall_k(
    const float* __restrict__ K_, const float* __restrict__ V_,
    const float* __restrict__ W1_, const float* __restrict__ W2_,
    u16* __restrict__ KhiA, u16* __restrict__ KloA,
    u16* __restrict__ VhiA, u16* __restrict__ VloA,
    u16* __restrict__ W1hiA, u16* __restrict__ W1loA,
    u16* __restrict__ W2hiA, u16* __restrict__ W2loA,
    int* __restrict__ counters)
{
    if (blockIdx.x == 0 && threadIdx.x < LL) counters[threadIdx.x] = 0;
    const int li  = blockIdx.x / 1600;
    const int sub = blockIdx.x % 1600;
#pragma unroll
    for (int jj = 0; jj < 2; jj++) {
        int i = sub * 512 + jj * 256 + threadIdx.x;  // float4 idx in layer
        const float* s;
        u16 *h, *l;
        int off;
        if (i < 32768) {
            s = K_ + (long)li * 131072;
            h = KhiA + (long)li * 131072;  l = KloA + (long)li * 131072;
            off = i;
        } else if (i < 294912) {
            s = V_ + (long)li * 1048576;
            h = VhiA + (long)li * 1048576; l = VloA + (long)li * 1048576;
            off = i - 32768;
        } else if (i < 557056) {
            s = W1_ + (long)li * 1048576;
            h = W1hiA + (long)li * 1048576; l = W1loA + (long)li * 1048576;
            off = i - 294912;
        } else {
            s = W2_ + (long)li * 1048576;
            h = W2hiA + (long)li * 1048576; l = W2loA + (long)li * 1048576;
            off = i - 557056;
        }
        float4 v = ((const float4*)s)[off];
        ushort4 hv, lv;
        splitf(v.x, hv.x, lv.x);
        splitf(v.y, hv.y, lv.y);
        splitf(v.z, hv.z, lv.z);
        splitf(v.w, hv.w, lv.w);
        ((ushort4*)h)[off] = hv;
        ((ushort4*)l)[off] = lv;
    }
}

__global__ __launch_bounds__(256) void apply_k(
    const unsigned int* __restrict__ csr, const int* __restrict__ colOff,
    const unsigned* __restrict__ rowmaxU, const int* __restrict__ rowcnt,
    const float* __restrict__ Yt, float* __restrict__ attnT)
{
    const int total = colOff[NN];
    const int tid = threadIdx.x;

    for (int base = blockIdx.x * CHUNK; base < total;
         base += gridDim.x * CHUNK) {
        int end = base + CHUNK;
        if (end > total) end = total;

        float a0 = 0.0f, a1 = 0.0f;
        int curM = -1;
        for (int e = base; e < end; e++) {
            unsigned v = csr[e];
            int m = v & 2047;
            int row = (int)(v >> 11);
            if (m != curM) {
                if (curM >= 0) {
                    atomicAdd(&attnT[(long)curM * DD + tid], a0);
                    atomicAdd(&attnT[(long)curM * DD + tid + 256], a1);
                }
                curM = m;
                a0 = a1 = 0.0f;
            }
            float mx = unmapf(rowmaxU[row]);
            float w = (fabsf(mx) > 0.5f)
                          ? 1.0f / fmaxf((float)rowcnt[row], 1.0f) : 0.0f;
            const float* y = Yt + (long)row * DD;
            a0 += w * y[tid];
            a1 += w * y[tid + 256];
        }
        if (curM >= 0) {
            atomicAdd(&attnT[(long)curM * DD + tid], a0);
            atomicAdd(&attnT[(long)curM * DD + tid + 256], a1);
        }
    }
}

__global__ __launch_bounds__(256) void ff2red_k(
    const float* __restrict__ Cpart, const float* __restrict__ b2,
    float* __restrict__ attnT, float* __restrict__ Xn,
    u16* __restrict__ Xhi, u16* __restrict__ Xlo)
{
    int i = blockIdx.x * 256 + threadIdx.x;
    float4 v0 = ((const float4*)(Cpart))[i];
    float4 v1 = ((const float4*)(Cpart + 1048576))[i];
    float4 v2 = ((const float4*)(Cpart + 2097152))[i];
    float4 v3 = ((const float4*)(Cpart + 3145728))[i];
    float4 bv = ((const float4*)b2)[i & 127];
    float4 rv = ((const float4*)attnT)[i];
    float4 o;
    o.x = v0.x + v1.x + v2.x + v3.x + bv.x + rv.x;
    o.y = v0.y + v1.y + v2.y + v3.y + bv.y + rv.y;
    o.z = v0.z + v1.z + v2.z + v3.z + bv.z + rv.z;
    o.w = v0.w + v1.w + v2.w + v3.w + bv.w + rv.w;
    ((float4*)Xn)[i] = o;
    ((float4*)attnT)[i] = o;           // seed next layer's residual base
    ushort4 hv, lv;
    splitf(o.x, hv.x, lv.x);
    splitf(o.y, hv.y, lv.y);
    splitf(o.z, hv.z, lv.z);
    splitf(o.w, hv.w, lv.w);
    ((ushort4*)Xhi)[i] = hv;
    ((ushort4*)Xlo)[i] = lv;
}

__global__ __launch_bounds__(256) void transpose_k(
    const float* __restrict__ src, float* __restrict__ dst, int R, int C)
{
    __shared__ float t[32][33];
    int tx = threadIdx.x & 31, ty = threadIdx.x >> 5;
    int c0 = blockIdx.x * 32, r0 = blockIdx.y * 32;
#pragma unroll
    for (int k = 0; k < 4; k++)
        t[ty + 8 * k][tx] = src[(long)(r0 + ty + 8 * k) * C + c0 + tx];
    __syncthreads();
#pragma unroll
    for (int k = 0; k < 4; k++)
        dst[(long)(c0 + ty + 8 * k) * R + r0 + tx] = t[tx][ty + 8 * k];
}

// ---------------------------------------------------------------------------
// Workspace layout (~193 MB < 256 MiB workspace).
// ---------------------------------------------------------------------------
extern "C" void kernel_launch(void* const* d_in, const int* in_sizes, int n_in,
                              void* d_out, int out_size, void* d_ws, size_t ws_size,
                              hipStream_t stream)
{
    const float* X0 = (const float*)d_in[0];
    const float* Kw = (const float*)d_in[1];
    const float* Vw = (const float*)d_in[2];
    const float* W1 = (const float*)d_in[3];
    const float* b1 = (const float*)d_in[4];
    const float* W2 = (const float*)d_in[5];
    const float* b2 = (const float*)d_in[6];
    float* out = (float*)d_out;

    float* R0    = (float*)d_ws;
    float* Yt    = R0;                       // 4,194,304  [H,NN,DD] fp32
    u16*   ff1hi = (u16*)(R0 + 4194304);
    u16*   ff1lo = (u16*)(R0 + 6291456);
    float* Cpart = R0 + 8388608;             // 4,194,304
    float* attnT = R0 + 12582912;            // 1,048,576

    float* ext = R0 + 13631488;
    u16* KXThi = (u16*)ext;                  // 262,144 words
    u16* KXTlo = (u16*)(ext + 262144);
    float* XbufA = ext + 524288;             // 1,048,576
    float* XbufB = ext + 1572864;            // 1,048,576
    u16* Xhi  = (u16*)(ext + 2621440);       // 524,288 words
    u16* Xlo  = (u16*)(ext + 3145728);
    u16* athi = (u16*)(ext + 3670016);
    u16* atlo = (u16*)(ext + 4194304);       // (ext+4718592 .. ext+8003583 free)
    unsigned int* entries = (unsigned int*)(ext + 8003584);  // 131,072
    unsigned int* csr     = (unsigned int*)(ext + 8134656);  // 131,072
    int* colOff   = (int*)(ext + 8265728);   // 2,112
    int* counters = (int*)(ext + 8267840);   // 64
    // contiguous zero region (ZWORDS = 151,552 u32):
    unsigned* rowmaxU = (unsigned*)(ext + 8267904);  // 8,192
    int* rowcnt   = (int*)(ext + 8276096);           // 8,192
    unsigned* colcnt = (unsigned*)(ext + 8284288);   // 2,048
    unsigned* tmaxU = (unsigned*)(ext + 8286336);    // 131,072
    int* colCur   = (int*)(ext + 8417408);           // 2,048 (zero-based cursors)
    // all-layer weight splits (u16), 104.9 MB:
    u16* wbase = (u16*)(ext + 8419456);
    u16* KhiA  = wbase;                         // 8 x 131,072
    u16* KloA  = wbase + 1048576;
    u16* VhiA  = wbase + 2097152;               // 8 x 1,048,576
    u16* VloA  = wbase + 10485760;
    u16* W1hiA = wbase + 18874368;
    u16* W1loA = wbase + 27262976;
    u16* W2hiA = wbase + 35651584;
    u16* W2loA = wbase + 44040192;              // ends at 52,428,800 u16

    // all-layer weight split (hoisted) + counters zero
    splitall_k<<<dim3(LL * 1600), 256, 0, stream>>>(
        Kw, Vw, W1, W2, KhiA, KloA, VhiA, VloA, W1hiA, W1loA, W2hiA, W2loA,
        counters);

    // XT0 = X0^T [N, D]; split to bf16 hi/lo and seed attnT = XT0
    transpose_k<<<dim3(NN / 32, DD / 32), 256, 0, stream>>>(X0, XbufA, DD, NN);
    splitc_k<<<dim3(1024), 256, 0, stream>>>(XbufA, Xhi, Xlo, attnT);

    float* Xc = XbufA;
    for (int li = 0; li < LL; li++) {
        float* Xn = (li & 1) ? XbufA : XbufB;
        u16* Khi = KhiA + (long)li * 131072;
        u16* Klo = KloA + (long)li * 131072;
        u16* Vhi = VhiA + (long)li * 1048576;
        u16* Vlo = VloA + (long)li * 1048576;
        u16* W1hi = W1hiA + (long)li * 1048576;
        u16* W1lo = W1loA + (long)li * 1048576;
        u16* W2hi = W2hiA + (long)li * 1048576;
        u16* W2lo = W2loA + (long)li * 1048576;

        // 1) KXT = XT @ Kw^T  [2048, 256], K=512 -> hi/lo. MI=1: 128 blocks.
        //    Prologue zero-sweeps rowmax/rowcnt/colcnt/tmax/colCur.
        mgemm_k<1, 0, 0, 0, 1><<<dim3(2, 64, 1), 256, 0, stream>>>(
            Xhi, Xlo, Khi, Klo, nullptr, KXThi, KXTlo, nullptr,
            NN, HH * QQ, DD, DD, DD, HH * QQ, 0, 0, 0,
            rowmaxU, ZWORDS);

        // 2) fused mask path: no S materialization; scatter builds CSR
        //    (incl. the colOff scan, block-locally) in one kernel.
        smax_k<<<dim3(16, 16, HH), 256, 0, stream>>>(KXThi, KXTlo, rowmaxU, tmaxU);
        sextract_k<<<dim3(16, 16, HH), 256, 0, stream>>>(
            KXThi, KXTlo, rowmaxU, tmaxU, rowcnt, colcnt, entries, counters + li);
        scatter_k<<<dim3(64), 256, 0, stream>>>(
            entries, counters + li, colcnt, csr, colOff, colCur);

        // 4) Yt_h = XT @ V_h^T  [NN, DD] fp32, batch H. 8-wave: 64 blk/head.
        mgemm8_k<0, 0, 1, 0><<<dim3(4, 16, HH), 512, 0, stream>>>(
            Xhi, Xlo, Vhi, Vlo, Yt, nullptr, nullptr, nullptr,
            DD, DD, DD, DD, 0, (long)DD * DD, (long)NN * DD);

        // 5) attnT (= XT residual) += sparse combine; split for FF1 input
        apply_k<<<dim3(APPLY_BLOCKS), 256, 0, stream>>>(
            csr, colOff, rowmaxU, rowcnt, Yt, attnT);
        split_k<<<dim3(1024), 256, 0, stream>>>(attnT, athi, atlo);

        // 6) ff1 = relu(attnT @ W1^T + b1)  [NN, DFF] -> hi/lo. 256 blocks.
        mgemm8_k<1, 1, 0, 1><<<dim3(16, 16, 1), 512, 0, stream>>>(
            athi, atlo, W1hi, W1lo, nullptr, ff1hi, ff1lo,
            b1 + (long)li * DFFC,
            DD, DD, DD, DFFC, 0, 0, 0);

        // 7) FF2 split-K=4: 64 blocks x 4.
        mgemm8_k<0, 0, 1, 0><<<dim3(4, 16, 4), 512, 0, stream>>>(
            ff1hi, ff1lo, W2hi, W2lo, Cpart, nullptr, nullptr, nullptr,
            512, DFFC, DFFC, DD, 512, 512, (long)NN * DD);
        ff2red_k<<<dim3(1024), 256, 0, stream>>>(
            Cpart, b2 + (long)li * DD, attnT, Xn, Xhi, Xlo);

        Xc = Xn;
    }

    // out = XT_final^T  [D, N]
    transpose_k<<<dim3(DD / 32, NN / 32), 256, 0, stream>>>(Xc, out, NN, DD);
}